// Round 9
// baseline (2896.644 us; speedup 1.0000x reference)
//
#include <hip/hip_runtime.h>

#define NN 256
#define HD 128
#define GNN_NB 64
#define MLP_NB 64
#define NBLK 128
#define NTHR 512
#define MASTER_B (GNN_NB - 1)

// ws float offsets (cross-block-mutable data accessed ONLY via sc1 atomics)
#define HS0_OFF 0
#define HS1_OFF 32768
#define H1_OFF  65536
#define GF_OFF  98304    // 64 gnn arrival flags, stride 32 u32 (128B lines)
#define MF_OFF  100352   // 64 mlp progress flags, stride 32 u32
#define GEN_OFF 102400   // 8 replicated generation lines, stride 32 u32

// GNN-block LDS (floats)
#define STH_L 0      // [4][128] own h rows (persist across phases)
#define STM_L 512    // [4][128] combined m rows
#define PT_L  1024   // [8][4][128] partials (gather m, then matvec outputs)
// MLP-block LDS (floats)
#define TGT_L 0
#define PTM_L 2048
#define PT3_L 10240
#define HC_L  11264
#define CT_L  11776
#define CZ_L  12032
#define W2_L  12288
#define HP_L  12544
#define PART_L 12800
#define ANC_L 13312
#define LP_L  13344
#define LDS_FLOATS 13360

// ---- device-coherent access (relaxed agent atomics -> sc1, bypass L1/L2) ----
__device__ __forceinline__ float2 ldc_f2(const float* p) {
    unsigned long long u = __hip_atomic_load((const unsigned long long*)p,
                                             __ATOMIC_RELAXED, __HIP_MEMORY_SCOPE_AGENT);
    float2 r;
    r.x = __uint_as_float((unsigned)u);
    r.y = __uint_as_float((unsigned)(u >> 32));
    return r;
}
__device__ __forceinline__ void stc_f(float* p, float v) {
    __hip_atomic_store((unsigned*)p, __float_as_uint(v),
                       __ATOMIC_RELAXED, __HIP_MEMORY_SCOPE_AGENT);
}
__device__ __forceinline__ unsigned ldf(const unsigned* p) {
    return __hip_atomic_load(p, __ATOMIC_RELAXED, __HIP_MEMORY_SCOPE_AGENT);
}
__device__ __forceinline__ void stf(unsigned* p, unsigned v) {
    __hip_atomic_store(p, v, __ATOMIC_RELAXED, __HIP_MEMORY_SCOPE_AGENT);
}

// block barrier that does NOT drain vmcnt
__device__ __forceinline__ void bar_lds() {
    asm volatile("s_waitcnt lgkmcnt(0)\n\ts_barrier" ::: "memory");
}

// Hierarchical grid barrier: non-master stores arrival, polls one gen replica.
// Master (block 63) aggregates 63 arrivals (+ MLP progress at even phases),
// then publishes gen to 8 replicated lines.
__device__ __forceinline__ void gnnbar(unsigned* gf, unsigned* mf, unsigned* gen,
                                       unsigned ph, int mlpmin, bool isMaster, int b)
{
    __syncthreads();  // drains vmem -> this block's sc1 stores retired at IF
    const int tid = threadIdx.x;
    if (isMaster) {
        if (tid < GNN_NB - 1) {
            while (ldf(gf + tid * 32) < ph) __builtin_amdgcn_s_sleep(1);
        } else if (tid >= 64 && tid < 64 + MLP_NB && mlpmin > 0) {
            while (ldf(mf + (tid - 64) * 32) < (unsigned)mlpmin) __builtin_amdgcn_s_sleep(1);
        }
        __syncthreads();
        if (tid < 8) stf(gen + tid * 32, ph);
    } else {
        if (tid == 0) {
            stf(gf + b * 32, ph);
            while (ldf(gen + (b & 7) * 32) < ph) __builtin_amdgcn_s_sleep(1);
        }
        __syncthreads();
    }
    asm volatile("" ::: "memory");
}

#define ISS(i) \
    float2 va##i, vb##i, vc##i, vd##i; \
    if ((i) < nst) { \
        const float* p_ = gsrc + (i) * 32 * HD; \
        if ((un >> (4 * (i)    )) & 1u) va##i = ldc_f2(p_); \
        if ((un >> (4 * (i) + 1)) & 1u) vb##i = ldc_f2(p_ + HD); \
        if ((un >> (4 * (i) + 2)) & 1u) vc##i = ldc_f2(p_ + 2 * HD); \
        if ((un >> (4 * (i) + 3)) & 1u) vd##i = ldc_f2(p_ + 3 * HD); \
    }
#define ACCP(v, b) { \
    const float f0_ = (float)((s0 >> (b)) & 1u); \
    const float f1_ = (float)((s1 >> (b)) & 1u); \
    const float f2_ = (float)((s2 >> (b)) & 1u); \
    const float f3_ = (float)((s3 >> (b)) & 1u); \
    m0.x = fmaf(f0_, v.x, m0.x); m0.y = fmaf(f0_, v.y, m0.y); \
    m1.x = fmaf(f1_, v.x, m1.x); m1.y = fmaf(f1_, v.y, m1.y); \
    m2.x = fmaf(f2_, v.x, m2.x); m2.y = fmaf(f2_, v.y, m2.y); \
    m3.x = fmaf(f3_, v.x, m3.x); m3.y = fmaf(f3_, v.y, m3.y); }
#define ACC1(v, b) if ((un >> (b)) & 1u) { ACCP(v, b) }
#define CNS(i) if ((i) < nst) { ACC1(va##i, 4*(i)) ACC1(vb##i, 4*(i)+1) \
                                ACC1(vc##i, 4*(i)+2) ACC1(vd##i, 4*(i)+3) }

// One GNN layer for rows [R0, R0+3]. h rows live in STH (LDS), masks in scalar regs,
// gather loads sc1 direct-to-register, issue masked by wave-uniform union bit.
__device__ __forceinline__ void layer(const float* src, float* dst, const float* bias,
    const float* z, const float* pos_emb, float* lds,
    const float2 (&wsA)[16], const float2 (&wnA)[16],
    unsigned mk0, unsigned mk1, unsigned mk2, unsigned mk3,
    int R0, int rmax, int tgate, int tnew, int lane, int wv, int tid)
{
    const int rmaxblk = min(rmax, R0 + 3);
    const int nst = (rmaxblk + 31) >> 5;
    const unsigned s0 = (R0     < tgate) ? mk0 : 0u;
    const unsigned s1 = (R0 + 1 < tgate) ? mk1 : 0u;
    const unsigned s2 = (R0 + 2 < tgate) ? mk2 : 0u;
    const unsigned s3 = (R0 + 3 < tgate) ? mk3 : 0u;
    const unsigned un = s0 | s1 | s2 | s3;

    // new node: h row := z + pos_emb[tnew]
    if (tnew >= R0 && tnew < R0 + 4) {
        const int dr = tnew - R0;
        if (tid < HD) lds[STH_L + dr * HD + tid] = z[tid] + pos_emb[tnew * HD + tid];
    }

    // gather: wave wv owns src rows {32c + 4wv + ss}; masked loads all in flight
    const float* gsrc = src + wv * 4 * HD + 2 * lane;
    float2 m0 = make_float2(0.f, 0.f), m1 = m0, m2 = m0, m3 = m0;
    ISS(0) ISS(1) ISS(2) ISS(3) ISS(4) ISS(5) ISS(6) ISS(7)
    CNS(0) CNS(1) CNS(2) CNS(3) CNS(4) CNS(5) CNS(6) CNS(7)

    // publish m partials
    float* pt = lds + PT_L + (wv * 4) * HD + 2 * lane;
    *(float2*)pt = m0; *(float2*)(pt + HD) = m1;
    *(float2*)(pt + 2 * HD) = m2; *(float2*)(pt + 3 * HD) = m3;
    bar_lds();
    // combine partials -> STM
    {
        const int dr = tid >> 7, k = tid & 127;
        float s = 0.f;
#pragma unroll
        for (int w = 0; w < 8; ++w) s += lds[PT_L + (w * 4 + dr) * HD + k];
        lds[STM_L + dr * HD + k] = s;
    }
    bar_lds();
    // matvec over this wave's 16-k slice, 4 rows, cols (2*lane, 2*lane+1)
    const int ks = wv * 16;
    float2 a0 = make_float2(0.f, 0.f), a1 = a0, a2 = a0, a3 = a0;
#define MV(dr, areg) { \
    const float4 hp = *(const float4*)(lds + STH_L + (dr) * HD + ks + 4 * kq); \
    const float4 mp = *(const float4*)(lds + STM_L + (dr) * HD + ks + 4 * kq); \
    areg.x = fmaf(hp.x, wsA[4*kq].x,   fmaf(mp.x, wnA[4*kq].x,   areg.x)); \
    areg.y = fmaf(hp.x, wsA[4*kq].y,   fmaf(mp.x, wnA[4*kq].y,   areg.y)); \
    areg.x = fmaf(hp.y, wsA[4*kq+1].x, fmaf(mp.y, wnA[4*kq+1].x, areg.x)); \
    areg.y = fmaf(hp.y, wsA[4*kq+1].y, fmaf(mp.y, wnA[4*kq+1].y, areg.y)); \
    areg.x = fmaf(hp.z, wsA[4*kq+2].x, fmaf(mp.z, wnA[4*kq+2].x, areg.x)); \
    areg.y = fmaf(hp.z, wsA[4*kq+2].y, fmaf(mp.z, wnA[4*kq+2].y, areg.y)); \
    areg.x = fmaf(hp.w, wsA[4*kq+3].x, fmaf(mp.w, wnA[4*kq+3].x, areg.x)); \
    areg.y = fmaf(hp.w, wsA[4*kq+3].y, fmaf(mp.w, wnA[4*kq+3].y, areg.y)); }
#pragma unroll
    for (int kq = 0; kq < 4; ++kq) { MV(0, a0) MV(1, a1) MV(2, a2) MV(3, a3) }
#undef MV
    // publish matvec partials (reuse PT)
    *(float2*)pt = a0; *(float2*)(pt + HD) = a1;
    *(float2*)(pt + 2 * HD) = a2; *(float2*)(pt + 3 * HD) = a3;
    bar_lds();
    // final combine + bias + relu; keep in STH (next phase's h) + sc1 store
    {
        const int dr = tid >> 7, c = tid & 127;
        float o = bias[c];
#pragma unroll
        for (int w = 0; w < 8; ++w) o += lds[PT_L + (w * 4 + dr) * HD + c];
        o = fmaxf(o, 0.f);
        lds[STH_L + dr * HD + c] = o;
        const int R = R0 + dr;
        if (R <= rmaxblk) stc_f(dst + R * HD + c, o);
    }
}

// ---- MLP helpers (proven numerics) ----
__device__ __forceinline__ void ct_calc(const float* hsP, const float* pos_emb,
                                        const float* Wm1, float* lds, int s)
{
    const int tid = threadIdx.x;
    if (tid < 64) {
        const float2 v = ldc_f2(hsP + s * HD + 2 * tid);
        lds[HP_L + 2 * tid] = v.x; lds[HP_L + 2 * tid + 1] = v.y;
    } else if (tid < 128) {
        const int l2 = tid - 64;
        lds[HP_L + 128 + 2 * l2]     = pos_emb[s * HD + 2 * l2];
        lds[HP_L + 128 + 2 * l2 + 1] = pos_emb[s * HD + 2 * l2 + 1];
    }
    __syncthreads();
    const int c = tid & 255, half = tid >> 8;
    float acc = 0.f;
    const float* w = half ? (Wm1 + 384 * 256 + c) : (Wm1 + c);
    const float* hh = lds + HP_L + half * 128;
#pragma unroll 4
    for (int k = 0; k < HD; ++k) acc = fmaf(hh[k], w[k * 256], acc);
    lds[PART_L + half * 256 + c] = acc;
    __syncthreads();
    if (tid < 256)
        lds[CT_L + tid] = lds[CZ_L + tid] + lds[PART_L + tid] + lds[PART_L + 256 + tid];
}

__device__ __forceinline__ void mlp_step(const float* hsP, const float* bm2,
                                         const float4 (&wm)[16], float* lds, int mb, int s)
{
    const int tid = threadIdx.x, lane = tid & 63, wv = tid >> 6;
    const int ks = wv * 16;
    if (wv < 4) {
        const int i = 4 * mb + wv;
        float2 v = make_float2(0.f, 0.f);
        if (i < s) v = ldc_f2(hsP + i * HD + 2 * lane);
        *(float2*)(lds + HC_L + wv * HD + 2 * lane) = v;
    }
    __syncthreads();
    float4 a0 = make_float4(0.f, 0.f, 0.f, 0.f), a1 = a0, a2 = a0, a3 = a0;
#pragma unroll
    for (int kk = 0; kk < 16; ++kk) {
        const int k = ks + kk;
        const float h0 = lds[HC_L + 0 * HD + k];
        const float h1 = lds[HC_L + 1 * HD + k];
        const float h2 = lds[HC_L + 2 * HD + k];
        const float h3 = lds[HC_L + 3 * HD + k];
        const float4 w = wm[kk];
        a0.x = fmaf(h0, w.x, a0.x); a0.y = fmaf(h0, w.y, a0.y);
        a0.z = fmaf(h0, w.z, a0.z); a0.w = fmaf(h0, w.w, a0.w);
        a1.x = fmaf(h1, w.x, a1.x); a1.y = fmaf(h1, w.y, a1.y);
        a1.z = fmaf(h1, w.z, a1.z); a1.w = fmaf(h1, w.w, a1.w);
        a2.x = fmaf(h2, w.x, a2.x); a2.y = fmaf(h2, w.y, a2.y);
        a2.z = fmaf(h2, w.z, a2.z); a2.w = fmaf(h2, w.w, a2.w);
        a3.x = fmaf(h3, w.x, a3.x); a3.y = fmaf(h3, w.y, a3.y);
        a3.z = fmaf(h3, w.z, a3.z); a3.w = fmaf(h3, w.w, a3.w);
    }
    *(float4*)(lds + PTM_L + (wv * 4 + 0) * 256 + 4 * lane) = a0;
    *(float4*)(lds + PTM_L + (wv * 4 + 1) * 256 + 4 * lane) = a1;
    *(float4*)(lds + PTM_L + (wv * 4 + 2) * 256 + 4 * lane) = a2;
    *(float4*)(lds + PTM_L + (wv * 4 + 3) * 256 + 4 * lane) = a3;
    __syncthreads();
    {
        const int c = tid & 255, ci2 = (tid >> 8) * 2;
#pragma unroll
        for (int q = 0; q < 2; ++q) {
            const int ci = ci2 + q;
            float v = lds[CT_L + c];
#pragma unroll
            for (int w = 0; w < 8; ++w) v += lds[PTM_L + (w * 4 + ci) * 256 + c];
            lds[PT3_L + ci * 256 + c] = fmaxf(v, 0.f) * lds[W2_L + c];
        }
    }
    __syncthreads();
    if (wv < 4) {
        const int ci = wv, i = 4 * mb + ci;
        if (i < s) {
            float sd = lds[PT3_L + ci * 256 + lane] + lds[PT3_L + ci * 256 + 64 + lane]
                     + lds[PT3_L + ci * 256 + 128 + lane] + lds[PT3_L + ci * 256 + 192 + lane];
#pragma unroll
            for (int off = 32; off > 0; off >>= 1) sd += __shfl_xor(sd, off);
            if (lane == 0) {
                const unsigned* gtl = (const unsigned*)(lds + TGT_L) + s * 8;
                unsigned* ancl = (unsigned*)(lds + ANC_L);
                const float logit = sd + bm2[0];
                const float prob = 1.f / (1.f + expf(-logit));
                unsigned cnt = 0, has = 0;
#pragma unroll
                for (int w = 0; w < 8; ++w) {
                    const unsigned av = ancl[ci * 8 + w];
                    cnt += __popc(av);
                    has |= av & gtl[w];
                }
                const float supp = ldexpf(1.f, -(int)cnt);  // 0.5^cnt exact
                const float adj = prob * supp;
                const unsigned gt = (gtl[i >> 5] >> (i & 31)) & 1u;
                const float lpv = gt ? logf(adj + 1e-12f) : logf(1.f - adj + 1e-12f);
                atomicAdd((float*)(lds + LP_L), lpv);
                if (has | gt) ancl[ci * 8 + (s >> 5)] |= (1u << (s & 31));
            }
        }
    }
}

extern "C" __global__ void __launch_bounds__(NTHR, 2)
fused_gnn(const float* z, const int* targets, const float* pos_emb,
          const float* Ws1, const float* Wn1, const float* b1,
          const float* Ws2, const float* Wn2, const float* b2,
          const float* Wm1, const float* bm1, const float* Wm2, const float* bm2,
          const float* Wf, const float* bf, float* out, float* ws)
{
    __shared__ __align__(16) float lds[LDS_FLOATS];
    const int b = blockIdx.x;
    const int tid = threadIdx.x, lane = tid & 63, wv = tid >> 6;

    float* h1w = ws + H1_OFF;
    unsigned* gf  = (unsigned*)(ws + GF_OFF);
    unsigned* mf  = (unsigned*)(ws + MF_OFF);
    unsigned* gen = (unsigned*)(ws + GEN_OFF);
    float* lp_out = out + NN * NN + NN * 16;
    const int ks = wv * 16;

    if (b < GNN_NB) {
        const bool isM = (b == MASTER_B);
        const int R0 = b * 4;
        float2 ws1[16], wn1[16], ws2[16], wn2[16];
#pragma unroll
        for (int kk = 0; kk < 16; ++kk) {
            ws1[kk] = *(const float2*)(Ws1 + (ks + kk) * HD + 2 * lane);
            wn1[kk] = *(const float2*)(Wn1 + (ks + kk) * HD + 2 * lane);
            ws2[kk] = *(const float2*)(Ws2 + (ks + kk) * HD + 2 * lane);
            wn2[kk] = *(const float2*)(Wn2 + (ks + kk) * HD + 2 * lane);
        }
        // per-wave static gather masks: bit b <-> src row (b>>2)*32 + wv*4 + (b&3)
        unsigned mk0, mk1, mk2, mk3;
        {
            const int srcl = (lane < 32) ? (((lane >> 2) << 5) + wv * 4 + (lane & 3)) : 0;
#define BALLOT_MK(dr, dst) { \
            const int r_ = R0 + (dr); \
            const bool p_ = (lane < 32) && (srcl < r_) && (targets[r_ * NN + srcl] != 0); \
            const unsigned long long bm_ = __ballot(p_); \
            dst = (unsigned)__builtin_amdgcn_readfirstlane((int)(unsigned)bm_); }
            BALLOT_MK(0, mk0) BALLOT_MK(1, mk1) BALLOT_MK(2, mk2) BALLOT_MK(3, mk3)
#undef BALLOT_MK
        }
        // init: STH (h rows), Hs0 global, tgt output
        lds[STH_L + tid] = (b == 0 && tid < HD) ? z[tid] : 0.f;
        {
            const int dr = tid >> 7, c = tid & 127, r = R0 + dr;
            stc_f(ws + HS0_OFF + r * HD + c, (r == 0) ? z[c] : 0.f);
        }
        if (wv < 4) {
            const int r = R0 + wv;
            const int4 tv = ((const int4*)(targets + r * NN))[lane];
            float4 ov;
            ov.x = (4 * lane     < r) ? (float)tv.x : 0.f;
            ov.y = (4 * lane + 1 < r) ? (float)tv.y : 0.f;
            ov.z = (4 * lane + 2 < r) ? (float)tv.z : 0.f;
            ov.w = (4 * lane + 3 < r) ? (float)tv.w : 0.f;
            ((float4*)(out + r * NN))[lane] = ov;
        }

        gnnbar(gf, mf, gen, 1u, 0, isM, b);
        unsigned ph = 2;

        for (int t = 1; t <= 256; ++t) {
            const int s = t - 1;
            const float* hsP = ws + ((s & 1) ? HS1_OFF : HS0_OFF);
            float* hsN = ws + ((t & 1) ? HS1_OFF : HS0_OFF);
            const int rmax  = (t <= 255) ? t : 255;
            const int tgate = (t <= 255) ? t : 300;
            const int tnew  = (t <= 255) ? t : -1;

            if (R0 <= rmax)
                layer(hsP, h1w, b1, z, pos_emb, lds, ws1, wn1,
                      mk0, mk1, mk2, mk3, R0, rmax, tgate, tnew, lane, wv, tid);
            gnnbar(gf, mf, gen, ph, (t >= 3) ? (t - 2) : 0, isM, b); ph++;  // ph = 2t

            if (R0 <= rmax)
                layer(h1w, hsN, b2, z, pos_emb, lds, ws2, wn2,
                      mk0, mk1, mk2, mk3, R0, rmax, tgate, -1, lane, wv, tid);
            gnnbar(gf, mf, gen, ph, 0, isM, b); ph++;                        // ph = 2t+1
        }

        // X_out from STH (final Hs rows of this block)
        if (wv < 4) {
            const int r = R0 + wv;
            const float* strow = lds + STH_L + wv * HD;
            const int f = lane & 15, kp = lane >> 4;
            float sacc = 0.f;
#pragma unroll
            for (int k = 0; k < 32; ++k)
                sacc = fmaf(strow[kp * 32 + k], Wf[(kp * 32 + k) * 16 + f], sacc);
            sacc += __shfl_xor(sacc, 16);
            sacc += __shfl_xor(sacc, 32);
            if (lane < 16) out[NN * NN + r * 16 + f] = sacc + bf[f];
        }
    } else {
        // ---- MLP block: decoupled, trails the GNN via the gen counter ----
        const int mb = b - GNN_NB;
        float4 wm[16];
#pragma unroll
        for (int kk = 0; kk < 16; ++kk)
            wm[kk] = *(const float4*)(Wm1 + (128 + ks + kk) * 256 + 4 * lane);
        {
            unsigned* tg = (unsigned*)(lds + TGT_L);
            for (int rr = 0; rr < 32; ++rr) {
                const int r = wv * 32 + rr;
#pragma unroll
                for (int q = 0; q < 4; ++q) {
                    const int j = q * 64 + lane;
                    const unsigned long long bm = __ballot(j < r && targets[r * NN + j] != 0);
                    if (lane == 0) {
                        tg[r * 8 + 2 * q]     = (unsigned)bm;
                        tg[r * 8 + 2 * q + 1] = (unsigned)(bm >> 32);
                    }
                }
            }
        }
        if (tid < 256) {
            lds[W2_L + tid] = Wm2[tid];
            float acc = bm1[tid];
            for (int k = 0; k < HD; ++k) acc = fmaf(z[k], Wm1[(256 + k) * 256 + tid], acc);
            lds[CZ_L + tid] = acc;
        }
        if (tid < 32) ((unsigned*)(lds + ANC_L))[tid] = 0u;
        if (tid == 0) lds[LP_L] = 0.f;

        for (int s = 1; s <= 255; ++s) {
            // Hs(s) complete <=> gen >= 2s+1
            if (tid == 0) {
                const unsigned need = 2u * (unsigned)s + 1u;
                while (ldf(gen + (b & 7) * 32) < need) __builtin_amdgcn_s_sleep(1);
            }
            __syncthreads();
            const float* hsP = ws + ((s & 1) ? HS1_OFF : HS0_OFF);
            if (4 * mb < s) {
                ct_calc(hsP, pos_emb, Wm1, lds, s);
                __syncthreads();
                mlp_step(hsP, bm2, wm, lds, mb, s);
            }
            __syncthreads();  // all reads of Hs(s) done (vmcnt drained per wave)
            if (tid == 0) stf(mf + mb * 32, (unsigned)s);
        }
        __syncthreads();
        if (tid == 0) atomicAdd(lp_out, lds[LP_L]);
    }
}

extern "C" void kernel_launch(void* const* d_in, const int* in_sizes, int n_in,
                              void* d_out, int out_size, void* d_ws, size_t ws_size,
                              hipStream_t stream)
{
    const float* z       = (const float*)d_in[0];
    const int*   targets = (const int*)d_in[1];
    const float* pos_emb = (const float*)d_in[2];
    const float* Ws1     = (const float*)d_in[3];
    const float* Wn1     = (const float*)d_in[4];
    const float* b1      = (const float*)d_in[5];
    const float* Ws2     = (const float*)d_in[6];
    const float* Wn2     = (const float*)d_in[7];
    const float* b2      = (const float*)d_in[8];
    const float* Wm1     = (const float*)d_in[9];
    const float* bm1     = (const float*)d_in[10];
    const float* Wm2     = (const float*)d_in[11];
    const float* bm2     = (const float*)d_in[12];
    const float* Wf      = (const float*)d_in[13];
    const float* bf      = (const float*)d_in[14];
    float* out = (float*)d_out;
    float* ws  = (float*)d_ws;

    // zero all flag lines (gf + mf + gen) and the lp accumulator each call
    (void)hipMemsetAsync(ws + GF_OFF, 0, (64 + 64 + 8) * 32 * sizeof(unsigned), stream);
    (void)hipMemsetAsync(out + NN * NN + NN * 16, 0, sizeof(float), stream);

    void* args[17] = {
        (void*)&z, (void*)&targets, (void*)&pos_emb,
        (void*)&Ws1, (void*)&Wn1, (void*)&b1,
        (void*)&Ws2, (void*)&Wn2, (void*)&b2,
        (void*)&Wm1, (void*)&bm1, (void*)&Wm2, (void*)&bm2,
        (void*)&Wf, (void*)&bf, (void*)&out, (void*)&ws
    };
    (void)hipLaunchCooperativeKernel((const void*)fused_gnn, dim3(NBLK), dim3(NTHR),
                                     args, 0, stream);
}

// Round 10
// 1982.241 us; speedup vs baseline: 1.4613x; 1.4613x over previous
//
#include <hip/hip_runtime.h>

#define NN 256
#define HD 128
#define GNN_NB 64
#define MLP_NB 64
#define NBLK 128
#define NTHR 512
#define D_HS 3
#define D_H1 2

// ws float offsets (cross-block-mutable data accessed ONLY via sc1 atomics)
#define HS_OFF 0                   // ring: 3 x 32768 floats
#define H1R_OFF 98304              // ring: 2 x 32768 floats
#define PROG_OFF 163840            // 64 gnn progress lines, stride 32 u32
#define MF_OFF   (163840 + 2048)   // 64 mlp progress lines, stride 32 u32

// GNN-block LDS (floats)
#define STH_L 0      // [4][128] own h rows (persist across phases)
#define STM_L 512    // [4][128] combined m rows
#define PT_L  1024   // [8][4][128] partials (gather m, then matvec outputs)
// MLP-block LDS (floats)
#define TGT_L 0
#define PTM_L 2048
#define PT3_L 10240
#define HC_L  11264
#define CT_L  11776
#define CZ_L  12032
#define W2_L  12288
#define HP_L  12544
#define PART_L 12800
#define ANC_L 13312
#define LP_L  13344
#define LDS_FLOATS 13360

// ---- device-coherent access (relaxed agent atomics -> sc1, bypass L1/L2) ----
__device__ __forceinline__ float2 ldc_f2(const float* p) {
    unsigned long long u = __hip_atomic_load((const unsigned long long*)p,
                                             __ATOMIC_RELAXED, __HIP_MEMORY_SCOPE_AGENT);
    float2 r;
    r.x = __uint_as_float((unsigned)u);
    r.y = __uint_as_float((unsigned)(u >> 32));
    return r;
}
__device__ __forceinline__ void stc_f(float* p, float v) {
    __hip_atomic_store((unsigned*)p, __float_as_uint(v),
                       __ATOMIC_RELAXED, __HIP_MEMORY_SCOPE_AGENT);
}
__device__ __forceinline__ unsigned ldf(const unsigned* p) {
    return __hip_atomic_load(p, __ATOMIC_RELAXED, __HIP_MEMORY_SCOPE_AGENT);
}
__device__ __forceinline__ void stf(unsigned* p, unsigned v) {
    __hip_atomic_store(p, v, __ATOMIC_RELAXED, __HIP_MEMORY_SCOPE_AGENT);
}

// block barrier that does NOT drain vmcnt
__device__ __forceinline__ void bar_lds() {
    asm volatile("s_waitcnt lgkmcnt(0)\n\ts_barrier" ::: "memory");
}

// Wait: tid<64 polls gnn prog (data threshold for b'<b, ring threshold for all);
// tid 64..127 polls mlp progress (ring guard).
__device__ __forceinline__ void wait_gnn(const unsigned* prog, const unsigned* mf,
                                         int b, unsigned dataTh, unsigned ringTh, int mlpTh)
{
    const int tid = threadIdx.x;
    if (tid < GNN_NB) {
        const unsigned th = (tid < b) ? dataTh : ringTh;  // dataTh >= ringTh always
        if (th)
            while (ldf(prog + tid * 32) < th) __builtin_amdgcn_s_sleep(1);
    } else if (tid < 2 * GNN_NB) {
        if (mlpTh > 0)
            while ((int)ldf(mf + (tid - GNN_NB) * 32) < mlpTh) __builtin_amdgcn_s_sleep(1);
    }
    __syncthreads();
    asm volatile("" ::: "memory");
}

#define ISS(i) \
    float2 va##i, vb##i, vc##i, vd##i; \
    if ((i) < nst) { \
        const float* p_ = gsrc + (i) * 32 * HD; \
        if ((un >> (4 * (i)    )) & 1u) va##i = ldc_f2(p_); \
        if ((un >> (4 * (i) + 1)) & 1u) vb##i = ldc_f2(p_ + HD); \
        if ((un >> (4 * (i) + 2)) & 1u) vc##i = ldc_f2(p_ + 2 * HD); \
        if ((un >> (4 * (i) + 3)) & 1u) vd##i = ldc_f2(p_ + 3 * HD); \
    }
#define ACCP(v, b) { \
    const float f0_ = (float)((s0 >> (b)) & 1u); \
    const float f1_ = (float)((s1 >> (b)) & 1u); \
    const float f2_ = (float)((s2 >> (b)) & 1u); \
    const float f3_ = (float)((s3 >> (b)) & 1u); \
    m0.x = fmaf(f0_, v.x, m0.x); m0.y = fmaf(f0_, v.y, m0.y); \
    m1.x = fmaf(f1_, v.x, m1.x); m1.y = fmaf(f1_, v.y, m1.y); \
    m2.x = fmaf(f2_, v.x, m2.x); m2.y = fmaf(f2_, v.y, m2.y); \
    m3.x = fmaf(f3_, v.x, m3.x); m3.y = fmaf(f3_, v.y, m3.y); }
#define ACC1(v, b) if ((un >> (b)) & 1u) { ACCP(v, b) }
#define CNS(i) if ((i) < nst) { ACC1(va##i, 4*(i)) ACC1(vb##i, 4*(i)+1) \
                                ACC1(vc##i, 4*(i)+2) ACC1(vd##i, 4*(i)+3) }

// One GNN layer for rows [R0, R0+3]. h rows in STH (LDS), masks in scalar regs,
// gather loads sc1 direct-to-register, masked by wave-uniform union bit.
__device__ __forceinline__ void layer(const float* src, float* dst, const float* bias,
    const float* z, const float* pos_emb, float* lds,
    const float2 (&wsA)[16], const float2 (&wnA)[16],
    unsigned mk0, unsigned mk1, unsigned mk2, unsigned mk3,
    int R0, int rmax, int tgate, int tnew, int lane, int wv, int tid)
{
    const int rmaxblk = min(rmax, R0 + 3);
    const int nst = (rmaxblk + 31) >> 5;
    const unsigned s0 = (R0     < tgate) ? mk0 : 0u;
    const unsigned s1 = (R0 + 1 < tgate) ? mk1 : 0u;
    const unsigned s2 = (R0 + 2 < tgate) ? mk2 : 0u;
    const unsigned s3 = (R0 + 3 < tgate) ? mk3 : 0u;
    const unsigned un = s0 | s1 | s2 | s3;

    // new node: h row := z + pos_emb[tnew]
    if (tnew >= R0 && tnew < R0 + 4) {
        const int dr = tnew - R0;
        if (tid < HD) lds[STH_L + dr * HD + tid] = z[tid] + pos_emb[tnew * HD + tid];
    }

    // gather: wave wv owns src rows {32c + 4wv + ss}; masked loads all in flight
    const float* gsrc = src + wv * 4 * HD + 2 * lane;
    float2 m0 = make_float2(0.f, 0.f), m1 = m0, m2 = m0, m3 = m0;
    ISS(0) ISS(1) ISS(2) ISS(3) ISS(4) ISS(5) ISS(6) ISS(7)
    CNS(0) CNS(1) CNS(2) CNS(3) CNS(4) CNS(5) CNS(6) CNS(7)

    // publish m partials
    float* pt = lds + PT_L + (wv * 4) * HD + 2 * lane;
    *(float2*)pt = m0; *(float2*)(pt + HD) = m1;
    *(float2*)(pt + 2 * HD) = m2; *(float2*)(pt + 3 * HD) = m3;
    bar_lds();
    // combine partials -> STM
    {
        const int dr = tid >> 7, k = tid & 127;
        float s = 0.f;
#pragma unroll
        for (int w = 0; w < 8; ++w) s += lds[PT_L + (w * 4 + dr) * HD + k];
        lds[STM_L + dr * HD + k] = s;
    }
    bar_lds();
    // matvec over this wave's 16-k slice, 4 rows, cols (2*lane, 2*lane+1)
    const int ks = wv * 16;
    float2 a0 = make_float2(0.f, 0.f), a1 = a0, a2 = a0, a3 = a0;
#define MV(dr, areg) { \
    const float4 hp = *(const float4*)(lds + STH_L + (dr) * HD + ks + 4 * kq); \
    const float4 mp = *(const float4*)(lds + STM_L + (dr) * HD + ks + 4 * kq); \
    areg.x = fmaf(hp.x, wsA[4*kq].x,   fmaf(mp.x, wnA[4*kq].x,   areg.x)); \
    areg.y = fmaf(hp.x, wsA[4*kq].y,   fmaf(mp.x, wnA[4*kq].y,   areg.y)); \
    areg.x = fmaf(hp.y, wsA[4*kq+1].x, fmaf(mp.y, wnA[4*kq+1].x, areg.x)); \
    areg.y = fmaf(hp.y, wsA[4*kq+1].y, fmaf(mp.y, wnA[4*kq+1].y, areg.y)); \
    areg.x = fmaf(hp.z, wsA[4*kq+2].x, fmaf(mp.z, wnA[4*kq+2].x, areg.x)); \
    areg.y = fmaf(hp.z, wsA[4*kq+2].y, fmaf(mp.z, wnA[4*kq+2].y, areg.y)); \
    areg.x = fmaf(hp.w, wsA[4*kq+3].x, fmaf(mp.w, wnA[4*kq+3].x, areg.x)); \
    areg.y = fmaf(hp.w, wsA[4*kq+3].y, fmaf(mp.w, wnA[4*kq+3].y, areg.y)); }
#pragma unroll
    for (int kq = 0; kq < 4; ++kq) { MV(0, a0) MV(1, a1) MV(2, a2) MV(3, a3) }
#undef MV
    // publish matvec partials (reuse PT)
    *(float2*)pt = a0; *(float2*)(pt + HD) = a1;
    *(float2*)(pt + 2 * HD) = a2; *(float2*)(pt + 3 * HD) = a3;
    bar_lds();
    // final combine + bias + relu; keep in STH (next phase's h) + sc1 store
    {
        const int dr = tid >> 7, c = tid & 127;
        float o = bias[c];
#pragma unroll
        for (int w = 0; w < 8; ++w) o += lds[PT_L + (w * 4 + dr) * HD + c];
        o = fmaxf(o, 0.f);
        lds[STH_L + dr * HD + c] = o;
        const int R = R0 + dr;
        if (R <= rmaxblk) stc_f(dst + R * HD + c, o);
    }
}

// ---- MLP helpers (proven numerics) ----
__device__ __forceinline__ void ct_calc(const float* hsP, const float* pos_emb,
                                        const float* Wm1, float* lds, int s)
{
    const int tid = threadIdx.x;
    if (tid < 64) {
        const float2 v = ldc_f2(hsP + s * HD + 2 * tid);
        lds[HP_L + 2 * tid] = v.x; lds[HP_L + 2 * tid + 1] = v.y;
    } else if (tid < 128) {
        const int l2 = tid - 64;
        lds[HP_L + 128 + 2 * l2]     = pos_emb[s * HD + 2 * l2];
        lds[HP_L + 128 + 2 * l2 + 1] = pos_emb[s * HD + 2 * l2 + 1];
    }
    __syncthreads();
    const int c = tid & 255, half = tid >> 8;
    float acc = 0.f;
    const float* w = half ? (Wm1 + 384 * 256 + c) : (Wm1 + c);
    const float* hh = lds + HP_L + half * 128;
#pragma unroll 4
    for (int k = 0; k < HD; ++k) acc = fmaf(hh[k], w[k * 256], acc);
    lds[PART_L + half * 256 + c] = acc;
    __syncthreads();
    if (tid < 256)
        lds[CT_L + tid] = lds[CZ_L + tid] + lds[PART_L + tid] + lds[PART_L + 256 + tid];
}

__device__ __forceinline__ void mlp_step(const float* hsP, const float* bm2,
                                         const float4 (&wm)[16], float* lds, int mb, int s)
{
    const int tid = threadIdx.x, lane = tid & 63, wv = tid >> 6;
    const int ks = wv * 16;
    if (wv < 4) {
        const int i = 4 * mb + wv;
        float2 v = make_float2(0.f, 0.f);
        if (i < s) v = ldc_f2(hsP + i * HD + 2 * lane);
        *(float2*)(lds + HC_L + wv * HD + 2 * lane) = v;
    }
    __syncthreads();
    float4 a0 = make_float4(0.f, 0.f, 0.f, 0.f), a1 = a0, a2 = a0, a3 = a0;
#pragma unroll
    for (int kk = 0; kk < 16; ++kk) {
        const int k = ks + kk;
        const float h0 = lds[HC_L + 0 * HD + k];
        const float h1 = lds[HC_L + 1 * HD + k];
        const float h2 = lds[HC_L + 2 * HD + k];
        const float h3 = lds[HC_L + 3 * HD + k];
        const float4 w = wm[kk];
        a0.x = fmaf(h0, w.x, a0.x); a0.y = fmaf(h0, w.y, a0.y);
        a0.z = fmaf(h0, w.z, a0.z); a0.w = fmaf(h0, w.w, a0.w);
        a1.x = fmaf(h1, w.x, a1.x); a1.y = fmaf(h1, w.y, a1.y);
        a1.z = fmaf(h1, w.z, a1.z); a1.w = fmaf(h1, w.w, a1.w);
        a2.x = fmaf(h2, w.x, a2.x); a2.y = fmaf(h2, w.y, a2.y);
        a2.z = fmaf(h2, w.z, a2.z); a2.w = fmaf(h2, w.w, a2.w);
        a3.x = fmaf(h3, w.x, a3.x); a3.y = fmaf(h3, w.y, a3.y);
        a3.z = fmaf(h3, w.z, a3.z); a3.w = fmaf(h3, w.w, a3.w);
    }
    *(float4*)(lds + PTM_L + (wv * 4 + 0) * 256 + 4 * lane) = a0;
    *(float4*)(lds + PTM_L + (wv * 4 + 1) * 256 + 4 * lane) = a1;
    *(float4*)(lds + PTM_L + (wv * 4 + 2) * 256 + 4 * lane) = a2;
    *(float4*)(lds + PTM_L + (wv * 4 + 3) * 256 + 4 * lane) = a3;
    __syncthreads();
    {
        const int c = tid & 255, ci2 = (tid >> 8) * 2;
#pragma unroll
        for (int q = 0; q < 2; ++q) {
            const int ci = ci2 + q;
            float v = lds[CT_L + c];
#pragma unroll
            for (int w = 0; w < 8; ++w) v += lds[PTM_L + (w * 4 + ci) * 256 + c];
            lds[PT3_L + ci * 256 + c] = fmaxf(v, 0.f) * lds[W2_L + c];
        }
    }
    __syncthreads();
    if (wv < 4) {
        const int ci = wv, i = 4 * mb + ci;
        if (i < s) {
            float sd = lds[PT3_L + ci * 256 + lane] + lds[PT3_L + ci * 256 + 64 + lane]
                     + lds[PT3_L + ci * 256 + 128 + lane] + lds[PT3_L + ci * 256 + 192 + lane];
#pragma unroll
            for (int off = 32; off > 0; off >>= 1) sd += __shfl_xor(sd, off);
            if (lane == 0) {
                const unsigned* gtl = (const unsigned*)(lds + TGT_L) + s * 8;
                unsigned* ancl = (unsigned*)(lds + ANC_L);
                const float logit = sd + bm2[0];
                const float prob = 1.f / (1.f + expf(-logit));
                unsigned cnt = 0, has = 0;
#pragma unroll
                for (int w = 0; w < 8; ++w) {
                    const unsigned av = ancl[ci * 8 + w];
                    cnt += __popc(av);
                    has |= av & gtl[w];
                }
                const float supp = ldexpf(1.f, -(int)cnt);  // 0.5^cnt exact
                const float adj = prob * supp;
                const unsigned gt = (gtl[i >> 5] >> (i & 31)) & 1u;
                const float lpv = gt ? logf(adj + 1e-12f) : logf(1.f - adj + 1e-12f);
                atomicAdd((float*)(lds + LP_L), lpv);
                if (has | gt) ancl[ci * 8 + (s >> 5)] |= (1u << (s & 31));
            }
        }
    }
}

extern "C" __global__ void __launch_bounds__(NTHR, 2)
fused_gnn(const float* z, const int* targets, const float* pos_emb,
          const float* Ws1, const float* Wn1, const float* b1,
          const float* Ws2, const float* Wn2, const float* b2,
          const float* Wm1, const float* bm1, const float* Wm2, const float* bm2,
          const float* Wf, const float* bf, float* out, float* ws)
{
    __shared__ __align__(16) float lds[LDS_FLOATS];
    const int b = blockIdx.x;
    const int tid = threadIdx.x, lane = tid & 63, wv = tid >> 6;

    unsigned* prog = (unsigned*)(ws + PROG_OFF);
    unsigned* mf   = (unsigned*)(ws + MF_OFF);
    float* lp_out = out + NN * NN + NN * 16;
    const int ks = wv * 16;

    if (b < GNN_NB) {
        const int R0 = b * 4;
        float2 ws1[16], wn1[16], ws2[16], wn2[16];
#pragma unroll
        for (int kk = 0; kk < 16; ++kk) {
            ws1[kk] = *(const float2*)(Ws1 + (ks + kk) * HD + 2 * lane);
            wn1[kk] = *(const float2*)(Wn1 + (ks + kk) * HD + 2 * lane);
            ws2[kk] = *(const float2*)(Ws2 + (ks + kk) * HD + 2 * lane);
            wn2[kk] = *(const float2*)(Wn2 + (ks + kk) * HD + 2 * lane);
        }
        // per-wave static gather masks: bit b <-> src row (b>>2)*32 + wv*4 + (b&3)
        unsigned mk0, mk1, mk2, mk3;
        {
            const int srcl = (lane < 32) ? (((lane >> 2) << 5) + wv * 4 + (lane & 3)) : 0;
#define BALLOT_MK(dr, dst) { \
            const int r_ = R0 + (dr); \
            const bool p_ = (lane < 32) && (srcl < r_) && (targets[r_ * NN + srcl] != 0); \
            const unsigned long long bm_ = __ballot(p_); \
            dst = (unsigned)__builtin_amdgcn_readfirstlane((int)(unsigned)bm_); }
            BALLOT_MK(0, mk0) BALLOT_MK(1, mk1) BALLOT_MK(2, mk2) BALLOT_MK(3, mk3)
#undef BALLOT_MK
        }
        // init: STH, Hs(0) slot 0, tgt output
        lds[STH_L + tid] = (b == 0 && tid < HD) ? z[tid] : 0.f;
        {
            const int dr = tid >> 7, c = tid & 127, r = R0 + dr;
            stc_f(ws + HS_OFF + r * HD + c, (r == 0) ? z[c] : 0.f);
        }
        if (wv < 4) {
            const int r = R0 + wv;
            const int4 tv = ((const int4*)(targets + r * NN))[lane];
            float4 ov;
            ov.x = (4 * lane     < r) ? (float)tv.x : 0.f;
            ov.y = (4 * lane + 1 < r) ? (float)tv.y : 0.f;
            ov.z = (4 * lane + 2 < r) ? (float)tv.z : 0.f;
            ov.w = (4 * lane + 3 < r) ? (float)tv.w : 0.f;
            ((float4*)(out + r * NN))[lane] = ov;
        }
        __syncthreads();  // drain init stores
        if (tid == 0) stf(prog + b * 32, 1u);

        for (int t = 1; t <= 256; ++t) {
            const float* hsP = ws + HS_OFF + ((t - 1) % D_HS) * 32768;
            float* h1c = ws + H1R_OFF + (t & 1) * 32768;         // t % D_H1
            float* hsN = ws + HS_OFF + (t % D_HS) * 32768;
            const int rmax  = (t <= 255) ? t : 255;
            const int tgate = (t <= 255) ? t : 300;
            const int tnew  = (t <= 255) ? t : -1;
            const bool act = (R0 <= rmax);

            // layer1(t): data b'<b >= 2t-1; H1 ring (occupant t-2): all >= 2(t-2)+1
            if (act) {
                wait_gnn(prog, mf, b, 2u * t - 1u,
                         (t > D_H1) ? (2u * (t - D_H1) + 1u) : 0u, 0);
                layer(hsP, h1c, b1, z, pos_emb, lds, ws1, wn1,
                      mk0, mk1, mk2, mk3, R0, rmax, tgate, tnew, lane, wv, tid);
            }
            __syncthreads();
            if (tid == 0) stf(prog + b * 32, 2u * t);

            // layer2(t): data b'<b >= 2t; Hs ring (occupant t-3): all >= 2(t-3+1),
            // and MLP(t-3) done with Hs(t-3)
            if (act) {
                wait_gnn(prog, mf, b, 2u * t,
                         (t > D_HS) ? (2u * (t - D_HS + 1)) : 0u, t - D_HS);
                layer(h1c, hsN, b2, z, pos_emb, lds, ws2, wn2,
                      mk0, mk1, mk2, mk3, R0, rmax, tgate, -1, lane, wv, tid);
            }
            __syncthreads();
            if (tid == 0) stf(prog + b * 32, 2u * t + 1u);
        }

        // X_out from STH (final Hs rows of this block)
        if (wv < 4) {
            const int r = R0 + wv;
            const float* strow = lds + STH_L + wv * HD;
            const int f = lane & 15, kp = lane >> 4;
            float sacc = 0.f;
#pragma unroll
            for (int k = 0; k < 32; ++k)
                sacc = fmaf(strow[kp * 32 + k], Wf[(kp * 32 + k) * 16 + f], sacc);
            sacc += __shfl_xor(sacc, 16);
            sacc += __shfl_xor(sacc, 32);
            if (lane < 16) out[NN * NN + r * 16 + f] = sacc + bf[f];
        }
    } else {
        // ---- MLP block: trails the GNN via prog counters ----
        const int mb = b - GNN_NB;
        float4 wm[16];
#pragma unroll
        for (int kk = 0; kk < 16; ++kk)
            wm[kk] = *(const float4*)(Wm1 + (128 + ks + kk) * 256 + 4 * lane);
        {
            unsigned* tg = (unsigned*)(lds + TGT_L);
            for (int rr = 0; rr < 32; ++rr) {
                const int r = wv * 32 + rr;
#pragma unroll
                for (int q = 0; q < 4; ++q) {
                    const int j = q * 64 + lane;
                    const unsigned long long bm = __ballot(j < r && targets[r * NN + j] != 0);
                    if (lane == 0) {
                        tg[r * 8 + 2 * q]     = (unsigned)bm;
                        tg[r * 8 + 2 * q + 1] = (unsigned)(bm >> 32);
                    }
                }
            }
        }
        if (tid < 256) {
            lds[W2_L + tid] = Wm2[tid];
            float acc = bm1[tid];
            for (int k = 0; k < HD; ++k) acc = fmaf(z[k], Wm1[(256 + k) * 256 + tid], acc);
            lds[CZ_L + tid] = acc;
        }
        if (tid < 32) ((unsigned*)(lds + ANC_L))[tid] = 0u;
        if (tid == 0) lds[LP_L] = 0.f;

        for (int s = 1; s <= 255; ++s) {
            // Hs(s) complete <=> all gnn prog >= 2s+1
            if (tid < GNN_NB) {
                const unsigned need = 2u * (unsigned)s + 1u;
                while (ldf(prog + tid * 32) < need) __builtin_amdgcn_s_sleep(1);
            }
            __syncthreads();
            const float* hsP = ws + HS_OFF + (s % D_HS) * 32768;
            if (4 * mb < s) {
                ct_calc(hsP, pos_emb, Wm1, lds, s);
                __syncthreads();
                mlp_step(hsP, bm2, wm, lds, mb, s);
            }
            __syncthreads();  // all reads of Hs(s) done (vmcnt drained per wave)
            if (tid == 0) stf(mf + mb * 32, (unsigned)s);
        }
        __syncthreads();
        if (tid == 0) atomicAdd(lp_out, lds[LP_L]);
    }
}

extern "C" void kernel_launch(void* const* d_in, const int* in_sizes, int n_in,
                              void* d_out, int out_size, void* d_ws, size_t ws_size,
                              hipStream_t stream)
{
    const float* z       = (const float*)d_in[0];
    const int*   targets = (const int*)d_in[1];
    const float* pos_emb = (const float*)d_in[2];
    const float* Ws1     = (const float*)d_in[3];
    const float* Wn1     = (const float*)d_in[4];
    const float* b1      = (const float*)d_in[5];
    const float* Ws2     = (const float*)d_in[6];
    const float* Wn2     = (const float*)d_in[7];
    const float* b2      = (const float*)d_in[8];
    const float* Wm1     = (const float*)d_in[9];
    const float* bm1     = (const float*)d_in[10];
    const float* Wm2     = (const float*)d_in[11];
    const float* bm2     = (const float*)d_in[12];
    const float* Wf      = (const float*)d_in[13];
    const float* bf      = (const float*)d_in[14];
    float* out = (float*)d_out;
    float* ws  = (float*)d_ws;

    // zero prog + mf flag lines and the lp accumulator each call
    (void)hipMemsetAsync(ws + PROG_OFF, 0, 2 * GNN_NB * 32 * sizeof(unsigned), stream);
    (void)hipMemsetAsync(out + NN * NN + NN * 16, 0, sizeof(float), stream);

    void* args[17] = {
        (void*)&z, (void*)&targets, (void*)&pos_emb,
        (void*)&Ws1, (void*)&Wn1, (void*)&b1,
        (void*)&Ws2, (void*)&Wn2, (void*)&b2,
        (void*)&Wm1, (void*)&bm1, (void*)&Wm2, (void*)&bm2,
        (void*)&Wf, (void*)&bf, (void*)&out, (void*)&ws
    };
    (void)hipLaunchCooperativeKernel((const void*)fused_gnn, dim3(NBLK), dim3(NTHR),
                                     args, 0, stream);
}

// Round 11
// 1868.557 us; speedup vs baseline: 1.5502x; 1.0608x over previous
//
#include <hip/hip_runtime.h>

#define NN 256
#define HD 128
#define GNN_NB 128
#define MLP_NB 64
#define NBLK 192
#define NTHR 512
#define D_HS 3
#define D_H1 2

// ws float offsets (cross-block-mutable data accessed ONLY via sc1 atomics)
#define HS_OFF 0                    // ring: 3 x 32768 floats
#define H1R_OFF 98304               // ring: 2 x 32768 floats
#define PROG_OFF 163840             // 128 gnn progress lines, stride 32 u32
#define MF_OFF   (163840 + 4096)    // 64 mlp progress lines, stride 32 u32

// GNN-block LDS (floats)
#define STH_L 0      // [2][128] own h rows (persist across phases)
#define STM_L 256    // [2][128] combined m rows
#define PT_L  512    // [8][2][128] gather partials
// MLP-block LDS (floats)
#define TGT_L 0
#define PTM_L 2048
#define PT3_L 10240
#define HC_L  11264
#define CT_L  11776
#define CZ_L  12032
#define W2_L  12288
#define HP_L  12544
#define PART_L 12800
#define ANC_L 13312
#define LP_L  13344
#define LDS_FLOATS 13360

// ---- device-coherent access (relaxed agent atomics -> sc1, bypass L1/L2) ----
__device__ __forceinline__ float2 ldc_f2(const float* p) {
    unsigned long long u = __hip_atomic_load((const unsigned long long*)p,
                                             __ATOMIC_RELAXED, __HIP_MEMORY_SCOPE_AGENT);
    float2 r;
    r.x = __uint_as_float((unsigned)u);
    r.y = __uint_as_float((unsigned)(u >> 32));
    return r;
}
__device__ __forceinline__ void stc_f(float* p, float v) {
    __hip_atomic_store((unsigned*)p, __float_as_uint(v),
                       __ATOMIC_RELAXED, __HIP_MEMORY_SCOPE_AGENT);
}
__device__ __forceinline__ unsigned ldf(const unsigned* p) {
    return __hip_atomic_load(p, __ATOMIC_RELAXED, __HIP_MEMORY_SCOPE_AGENT);
}
__device__ __forceinline__ void stf(unsigned* p, unsigned v) {
    __hip_atomic_store(p, v, __ATOMIC_RELAXED, __HIP_MEMORY_SCOPE_AGENT);
}

// block barrier that does NOT drain vmcnt
__device__ __forceinline__ void bar_lds() {
    asm volatile("s_waitcnt lgkmcnt(0)\n\ts_barrier" ::: "memory");
}

// Wait: tid<128 polls gnn prog (data threshold for b'<b, ring threshold for all);
// tid 128..191 polls mlp progress (ring guard).
__device__ __forceinline__ void wait_gnn(const unsigned* prog, const unsigned* mf,
                                         int b, unsigned dataTh, unsigned ringTh, int mlpTh)
{
    const int tid = threadIdx.x;
    if (tid < GNN_NB) {
        const unsigned th = (tid < b) ? dataTh : ringTh;  // dataTh >= ringTh always
        if (th)
            while (ldf(prog + tid * 32) < th) __builtin_amdgcn_s_sleep(1);
    } else if (tid < GNN_NB + MLP_NB) {
        if (mlpTh > 0)
            while ((int)ldf(mf + (tid - GNN_NB) * 32) < mlpTh) __builtin_amdgcn_s_sleep(1);
    }
    __syncthreads();
    asm volatile("" ::: "memory");
}

#define ISS(i) \
    float2 va##i, vb##i, vc##i, vd##i; \
    if ((i) < nst) { \
        const float* p_ = gsrc + (i) * 32 * HD; \
        if ((un >> (4 * (i)    )) & 1u) va##i = ldc_f2(p_); \
        if ((un >> (4 * (i) + 1)) & 1u) vb##i = ldc_f2(p_ + HD); \
        if ((un >> (4 * (i) + 2)) & 1u) vc##i = ldc_f2(p_ + 2 * HD); \
        if ((un >> (4 * (i) + 3)) & 1u) vd##i = ldc_f2(p_ + 3 * HD); \
    }
#define ACCP(v, b) { \
    const float f0_ = (float)((s0 >> (b)) & 1u); \
    const float f1_ = (float)((s1 >> (b)) & 1u); \
    m0.x = fmaf(f0_, v.x, m0.x); m0.y = fmaf(f0_, v.y, m0.y); \
    m1.x = fmaf(f1_, v.x, m1.x); m1.y = fmaf(f1_, v.y, m1.y); }
#define ACC1(v, b) if ((un >> (b)) & 1u) { ACCP(v, b) }
#define CNS(i) if ((i) < nst) { ACC1(va##i, 4*(i)) ACC1(vb##i, 4*(i)+1) \
                                ACC1(vc##i, 4*(i)+2) ACC1(vd##i, 4*(i)+3) }

// One GNN layer for rows {R0, R0+1}. h rows in STH (LDS), masks in scalar regs,
// gather sc1 direct-to-register; matvec col-per-lane with shuffle k-reduce.
// Weights: lane covers col c = 16*wv + (lane&15), k-range [kbase, kbase+32).
__device__ __forceinline__ void layer(const float* src, float* dst, float bc,
    const float* z, const float* pos_emb, float* lds,
    const float (&wsA)[32], const float (&wnA)[32],
    unsigned mk0, unsigned mk1,
    int R0, int rmax, int tgate, int tnew, int lane, int wv, int tid, int c, int kbase)
{
    const int rmaxblk = min(rmax, R0 + 1);
    const int nst = (rmaxblk + 31) >> 5;  // chunks covering parent rows
    const unsigned s0 = (R0     < tgate) ? mk0 : 0u;
    const unsigned s1 = (R0 + 1 < tgate) ? mk1 : 0u;
    const unsigned un = s0 | s1;

    // new node: h row := z + pos_emb[tnew]
    if (tnew >= R0 && tnew < R0 + 2) {
        const int dr = tnew - R0;
        if (tid < HD) lds[STH_L + dr * HD + tid] = z[tid] + pos_emb[tnew * HD + tid];
    }

    // gather: wave wv owns src rows {32c' + 4wv + ss}; masked loads all in flight
    const float* gsrc = src + wv * 4 * HD + 2 * lane;
    float2 m0 = make_float2(0.f, 0.f), m1 = m0;
    ISS(0) ISS(1) ISS(2) ISS(3) ISS(4) ISS(5) ISS(6) ISS(7)
    CNS(0) CNS(1) CNS(2) CNS(3) CNS(4) CNS(5) CNS(6) CNS(7)

    // publish m partials
    float* pt = lds + PT_L + (wv * 2) * HD + 2 * lane;
    *(float2*)pt = m0;
    *(float2*)(pt + HD) = m1;
    bar_lds();
    // combine partials -> STM (2 rows x 128 k, threads 0..255)
    if (tid < 256) {
        const int dr = tid >> 7, k = tid & 127;
        float s = 0.f;
#pragma unroll
        for (int w = 0; w < 8; ++w) s += lds[PT_L + (w * 2 + dr) * HD + k];
        lds[STM_L + dr * HD + k] = s;
    }
    bar_lds();
    // matvec: lane accumulates its col over its 32-k slice, butterfly k-reduce
    float acc0 = 0.f, acc1 = 0.f;
#pragma unroll
    for (int q = 0; q < 8; ++q) {
        const float4 h0 = *(const float4*)(lds + STH_L + kbase + 4 * q);
        const float4 mm0 = *(const float4*)(lds + STM_L + kbase + 4 * q);
        const float4 h1 = *(const float4*)(lds + STH_L + HD + kbase + 4 * q);
        const float4 mm1 = *(const float4*)(lds + STM_L + HD + kbase + 4 * q);
        acc0 = fmaf(h0.x, wsA[4*q],   fmaf(mm0.x, wnA[4*q],   acc0));
        acc0 = fmaf(h0.y, wsA[4*q+1], fmaf(mm0.y, wnA[4*q+1], acc0));
        acc0 = fmaf(h0.z, wsA[4*q+2], fmaf(mm0.z, wnA[4*q+2], acc0));
        acc0 = fmaf(h0.w, wsA[4*q+3], fmaf(mm0.w, wnA[4*q+3], acc0));
        acc1 = fmaf(h1.x, wsA[4*q],   fmaf(mm1.x, wnA[4*q],   acc1));
        acc1 = fmaf(h1.y, wsA[4*q+1], fmaf(mm1.y, wnA[4*q+1], acc1));
        acc1 = fmaf(h1.z, wsA[4*q+2], fmaf(mm1.z, wnA[4*q+2], acc1));
        acc1 = fmaf(h1.w, wsA[4*q+3], fmaf(mm1.w, wnA[4*q+3], acc1));
    }
    acc0 += __shfl_xor(acc0, 16); acc0 += __shfl_xor(acc0, 32);
    acc1 += __shfl_xor(acc1, 16); acc1 += __shfl_xor(acc1, 32);
    const float o0 = fmaxf(acc0 + bc, 0.f);
    const float o1 = fmaxf(acc1 + bc, 0.f);
    // store + STH update, parallel across the 4 k-groups (all lanes hold both sums)
    const int kg = lane >> 4;
    if (kg == 0) { if (R0     <= rmaxblk) stc_f(dst + R0 * HD + c, o0); }
    else if (kg == 1) { if (R0 + 1 <= rmaxblk) stc_f(dst + (R0 + 1) * HD + c, o1); }
    else if (kg == 2) lds[STH_L + c] = o0;
    else              lds[STH_L + HD + c] = o1;
}

// ---- MLP helpers (proven numerics) ----
__device__ __forceinline__ void ct_calc(const float* hsP, const float* pos_emb,
                                        const float* Wm1, float* lds, int s)
{
    const int tid = threadIdx.x;
    if (tid < 64) {
        const float2 v = ldc_f2(hsP + s * HD + 2 * tid);
        lds[HP_L + 2 * tid] = v.x; lds[HP_L + 2 * tid + 1] = v.y;
    } else if (tid < 128) {
        const int l2 = tid - 64;
        lds[HP_L + 128 + 2 * l2]     = pos_emb[s * HD + 2 * l2];
        lds[HP_L + 128 + 2 * l2 + 1] = pos_emb[s * HD + 2 * l2 + 1];
    }
    __syncthreads();
    const int c = tid & 255, half = tid >> 8;
    float acc = 0.f;
    const float* w = half ? (Wm1 + 384 * 256 + c) : (Wm1 + c);
    const float* hh = lds + HP_L + half * 128;
#pragma unroll 4
    for (int k = 0; k < HD; ++k) acc = fmaf(hh[k], w[k * 256], acc);
    lds[PART_L + half * 256 + c] = acc;
    __syncthreads();
    if (tid < 256)
        lds[CT_L + tid] = lds[CZ_L + tid] + lds[PART_L + tid] + lds[PART_L + 256 + tid];
}

__device__ __forceinline__ void mlp_step(const float* hsP, const float* bm2,
                                         const float4 (&wm)[16], float* lds, int mb, int s)
{
    const int tid = threadIdx.x, lane = tid & 63, wv = tid >> 6;
    const int ks = wv * 16;
    if (wv < 4) {
        const int i = 4 * mb + wv;
        float2 v = make_float2(0.f, 0.f);
        if (i < s) v = ldc_f2(hsP + i * HD + 2 * lane);
        *(float2*)(lds + HC_L + wv * HD + 2 * lane) = v;
    }
    __syncthreads();
    float4 a0 = make_float4(0.f, 0.f, 0.f, 0.f), a1 = a0, a2 = a0, a3 = a0;
#pragma unroll
    for (int kk = 0; kk < 16; ++kk) {
        const int k = ks + kk;
        const float h0 = lds[HC_L + 0 * HD + k];
        const float h1 = lds[HC_L + 1 * HD + k];
        const float h2 = lds[HC_L + 2 * HD + k];
        const float h3 = lds[HC_L + 3 * HD + k];
        const float4 w = wm[kk];
        a0.x = fmaf(h0, w.x, a0.x); a0.y = fmaf(h0, w.y, a0.y);
        a0.z = fmaf(h0, w.z, a0.z); a0.w = fmaf(h0, w.w, a0.w);
        a1.x = fmaf(h1, w.x, a1.x); a1.y = fmaf(h1, w.y, a1.y);
        a1.z = fmaf(h1, w.z, a1.z); a1.w = fmaf(h1, w.w, a1.w);
        a2.x = fmaf(h2, w.x, a2.x); a2.y = fmaf(h2, w.y, a2.y);
        a2.z = fmaf(h2, w.z, a2.z); a2.w = fmaf(h2, w.w, a2.w);
        a3.x = fmaf(h3, w.x, a3.x); a3.y = fmaf(h3, w.y, a3.y);
        a3.z = fmaf(h3, w.z, a3.z); a3.w = fmaf(h3, w.w, a3.w);
    }
    *(float4*)(lds + PTM_L + (wv * 4 + 0) * 256 + 4 * lane) = a0;
    *(float4*)(lds + PTM_L + (wv * 4 + 1) * 256 + 4 * lane) = a1;
    *(float4*)(lds + PTM_L + (wv * 4 + 2) * 256 + 4 * lane) = a2;
    *(float4*)(lds + PTM_L + (wv * 4 + 3) * 256 + 4 * lane) = a3;
    __syncthreads();
    {
        const int c = tid & 255, ci2 = (tid >> 8) * 2;
#pragma unroll
        for (int q = 0; q < 2; ++q) {
            const int ci = ci2 + q;
            float v = lds[CT_L + c];
#pragma unroll
            for (int w = 0; w < 8; ++w) v += lds[PTM_L + (w * 4 + ci) * 256 + c];
            lds[PT3_L + ci * 256 + c] = fmaxf(v, 0.f) * lds[W2_L + c];
        }
    }
    __syncthreads();
    if (wv < 4) {
        const int ci = wv, i = 4 * mb + ci;
        if (i < s) {
            float sd = lds[PT3_L + ci * 256 + lane] + lds[PT3_L + ci * 256 + 64 + lane]
                     + lds[PT3_L + ci * 256 + 128 + lane] + lds[PT3_L + ci * 256 + 192 + lane];
#pragma unroll
            for (int off = 32; off > 0; off >>= 1) sd += __shfl_xor(sd, off);
            if (lane == 0) {
                const unsigned* gtl = (const unsigned*)(lds + TGT_L) + s * 8;
                unsigned* ancl = (unsigned*)(lds + ANC_L);
                const float logit = sd + bm2[0];
                const float prob = 1.f / (1.f + expf(-logit));
                unsigned cnt = 0, has = 0;
#pragma unroll
                for (int w = 0; w < 8; ++w) {
                    const unsigned av = ancl[ci * 8 + w];
                    cnt += __popc(av);
                    has |= av & gtl[w];
                }
                const float supp = ldexpf(1.f, -(int)cnt);  // 0.5^cnt exact
                const float adj = prob * supp;
                const unsigned gt = (gtl[i >> 5] >> (i & 31)) & 1u;
                const float lpv = gt ? logf(adj + 1e-12f) : logf(1.f - adj + 1e-12f);
                atomicAdd((float*)(lds + LP_L), lpv);
                if (has | gt) ancl[ci * 8 + (s >> 5)] |= (1u << (s & 31));
            }
        }
    }
}

extern "C" __global__ void __launch_bounds__(NTHR)
fused_gnn(const float* z, const int* targets, const float* pos_emb,
          const float* Ws1, const float* Wn1, const float* b1,
          const float* Ws2, const float* Wn2, const float* b2,
          const float* Wm1, const float* bm1, const float* Wm2, const float* bm2,
          const float* Wf, const float* bf, float* out, float* ws)
{
    __shared__ __align__(16) float lds[LDS_FLOATS];
    const int b = blockIdx.x;
    const int tid = threadIdx.x, lane = tid & 63, wv = tid >> 6;

    unsigned* prog = (unsigned*)(ws + PROG_OFF);
    unsigned* mf   = (unsigned*)(ws + MF_OFF);
    float* lp_out = out + NN * NN + NN * 16;

    if (b < GNN_NB) {
        const int R0 = b * 2;
        const int c = 16 * wv + (lane & 15);     // this lane's output column
        const int kbase = 32 * (lane >> 4);      // this lane's k-slice
        // weights into registers (both layers): w[i] = W[(kbase+i)][c]
        float ws1[32], wn1[32], ws2[32], wn2[32];
#pragma unroll
        for (int i = 0; i < 32; ++i) {
            ws1[i] = Ws1[(kbase + i) * HD + c];
            wn1[i] = Wn1[(kbase + i) * HD + c];
            ws2[i] = Ws2[(kbase + i) * HD + c];
            wn2[i] = Wn2[(kbase + i) * HD + c];
        }
        const float b1c = b1[c], b2c = b2[c];
        // per-wave static gather masks: bit bb <-> src row (bb>>2)*32 + 4wv + (bb&3)
        unsigned mk0, mk1;
        {
            const int srcl = (lane < 32) ? (((lane >> 2) << 5) + wv * 4 + (lane & 3)) : 0;
#define BALLOT_MK(dr, dst) { \
            const int r_ = R0 + (dr); \
            const bool p_ = (lane < 32) && (srcl < r_) && (targets[r_ * NN + srcl] != 0); \
            const unsigned long long bm_ = __ballot(p_); \
            dst = (unsigned)__builtin_amdgcn_readfirstlane((int)(unsigned)bm_); }
            BALLOT_MK(0, mk0) BALLOT_MK(1, mk1)
#undef BALLOT_MK
        }
        // init: STH rows, Hs(0) slot 0, tgt output
        if (tid < 256) lds[STH_L + tid] = (b == 0 && tid < HD) ? z[tid] : 0.f;
        if (tid < 256) {
            const int dr = tid >> 7, cc = tid & 127, r = R0 + dr;
            stc_f(ws + HS_OFF + r * HD + cc, (r == 0) ? z[cc] : 0.f);
        }
        if (wv < 2) {
            const int r = R0 + wv;
            const int4 tv = ((const int4*)(targets + r * NN))[lane];
            float4 ov;
            ov.x = (4 * lane     < r) ? (float)tv.x : 0.f;
            ov.y = (4 * lane + 1 < r) ? (float)tv.y : 0.f;
            ov.z = (4 * lane + 2 < r) ? (float)tv.z : 0.f;
            ov.w = (4 * lane + 3 < r) ? (float)tv.w : 0.f;
            ((float4*)(out + r * NN))[lane] = ov;
        }
        __syncthreads();  // drain init stores
        if (tid == 0) stf(prog + b * 32, 1u);

        for (int t = 1; t <= 256; ++t) {
            const float* hsP = ws + HS_OFF + ((t - 1) % D_HS) * 32768;
            float* h1c = ws + H1R_OFF + (t & 1) * 32768;        // t % D_H1
            float* hsN = ws + HS_OFF + (t % D_HS) * 32768;
            const int rmax  = (t <= 255) ? t : 255;
            const int tgate = (t <= 255) ? t : 300;
            const int tnew  = (t <= 255) ? t : -1;
            const bool act = (R0 <= rmax);

            // layer1(t): data b'<b >= 2t-1; H1 ring (occupant t-2): all >= 2(t-2)+1
            if (act) {
                wait_gnn(prog, mf, b, 2u * t - 1u,
                         (t > D_H1) ? (2u * (t - D_H1) + 1u) : 0u, 0);
                layer(hsP, h1c, b1c, z, pos_emb, lds, ws1, wn1,
                      mk0, mk1, R0, rmax, tgate, tnew, lane, wv, tid, c, kbase);
            }
            __syncthreads();
            if (tid == 0) stf(prog + b * 32, 2u * t);

            // layer2(t): data b'<b >= 2t; Hs ring (occupant t-3): all >= 2(t-2),
            // and MLP(t-3) done with Hs(t-3)
            if (act) {
                wait_gnn(prog, mf, b, 2u * t,
                         (t > D_HS) ? (2u * (t - D_HS + 1)) : 0u, t - D_HS);
                layer(h1c, hsN, b2c, z, pos_emb, lds, ws2, wn2,
                      mk0, mk1, R0, rmax, tgate, -1, lane, wv, tid, c, kbase);
            }
            __syncthreads();
            if (tid == 0) stf(prog + b * 32, 2u * t + 1u);
        }

        // X_out from STH (final Hs rows of this block)
        if (wv < 2) {
            const int r = R0 + wv;
            const float* strow = lds + STH_L + wv * HD;
            const int f = lane & 15, kp = lane >> 4;
            float sacc = 0.f;
#pragma unroll
            for (int k = 0; k < 32; ++k)
                sacc = fmaf(strow[kp * 32 + k], Wf[(kp * 32 + k) * 16 + f], sacc);
            sacc += __shfl_xor(sacc, 16);
            sacc += __shfl_xor(sacc, 32);
            if (lane < 16) out[NN * NN + r * 16 + f] = sacc + bf[f];
        }
    } else {
        // ---- MLP block: trails the GNN via prog counters ----
        const int mb = b - GNN_NB;
        const int ks = wv * 16;
        float4 wm[16];
#pragma unroll
        for (int kk = 0; kk < 16; ++kk)
            wm[kk] = *(const float4*)(Wm1 + (128 + ks + kk) * 256 + 4 * lane);
        {
            unsigned* tg = (unsigned*)(lds + TGT_L);
            for (int rr = 0; rr < 32; ++rr) {
                const int r = wv * 32 + rr;
#pragma unroll
                for (int q = 0; q < 4; ++q) {
                    const int j = q * 64 + lane;
                    const unsigned long long bm = __ballot(j < r && targets[r * NN + j] != 0);
                    if (lane == 0) {
                        tg[r * 8 + 2 * q]     = (unsigned)bm;
                        tg[r * 8 + 2 * q + 1] = (unsigned)(bm >> 32);
                    }
                }
            }
        }
        if (tid < 256) {
            lds[W2_L + tid] = Wm2[tid];
            float acc = bm1[tid];
            for (int k = 0; k < HD; ++k) acc = fmaf(z[k], Wm1[(256 + k) * 256 + tid], acc);
            lds[CZ_L + tid] = acc;
        }
        if (tid < 32) ((unsigned*)(lds + ANC_L))[tid] = 0u;
        if (tid == 0) lds[LP_L] = 0.f;

        for (int s = 1; s <= 255; ++s) {
            // Hs(s) complete <=> all gnn prog >= 2s+1
            if (tid < GNN_NB) {
                const unsigned need = 2u * (unsigned)s + 1u;
                while (ldf(prog + tid * 32) < need) __builtin_amdgcn_s_sleep(1);
            }
            __syncthreads();
            const float* hsP = ws + HS_OFF + (s % D_HS) * 32768;
            if (4 * mb < s) {
                ct_calc(hsP, pos_emb, Wm1, lds, s);
                __syncthreads();
                mlp_step(hsP, bm2, wm, lds, mb, s);
            }
            __syncthreads();  // all reads of Hs(s) done (vmcnt drained per wave)
            if (tid == 0) stf(mf + mb * 32, (unsigned)s);
        }
        __syncthreads();
        if (tid == 0) atomicAdd(lp_out, lds[LP_L]);
    }
}

extern "C" void kernel_launch(void* const* d_in, const int* in_sizes, int n_in,
                              void* d_out, int out_size, void* d_ws, size_t ws_size,
                              hipStream_t stream)
{
    const float* z       = (const float*)d_in[0];
    const int*   targets = (const int*)d_in[1];
    const float* pos_emb = (const float*)d_in[2];
    const float* Ws1     = (const float*)d_in[3];
    const float* Wn1     = (const float*)d_in[4];
    const float* b1      = (const float*)d_in[5];
    const float* Ws2     = (const float*)d_in[6];
    const float* Wn2     = (const float*)d_in[7];
    const float* b2      = (const float*)d_in[8];
    const float* Wm1     = (const float*)d_in[9];
    const float* bm1     = (const float*)d_in[10];
    const float* Wm2     = (const float*)d_in[11];
    const float* bm2     = (const float*)d_in[12];
    const float* Wf      = (const float*)d_in[13];
    const float* bf      = (const float*)d_in[14];
    float* out = (float*)d_out;
    float* ws  = (float*)d_ws;

    // zero prog + mf flag lines and the lp accumulator each call
    (void)hipMemsetAsync(ws + PROG_OFF, 0, (GNN_NB + MLP_NB) * 32 * sizeof(unsigned), stream);
    (void)hipMemsetAsync(out + NN * NN + NN * 16, 0, sizeof(float), stream);

    void* args[17] = {
        (void*)&z, (void*)&targets, (void*)&pos_emb,
        (void*)&Ws1, (void*)&Wn1, (void*)&b1,
        (void*)&Ws2, (void*)&Wn2, (void*)&b2,
        (void*)&Wm1, (void*)&bm1, (void*)&Wm2, (void*)&bm2,
        (void*)&Wf, (void*)&bf, (void*)&out, (void*)&ws
    };
    (void)hipLaunchCooperativeKernel((const void*)fused_gnn, dim3(NBLK), dim3(NTHR),
                                     args, 0, stream);
}

// Round 12
// 1818.020 us; speedup vs baseline: 1.5933x; 1.0278x over previous
//
#include <hip/hip_runtime.h>

#define NN 256
#define HD 128
#define GNN_NB 128
#define MLP_NB 64
#define NBLK 192
#define NTHR 512
#define D_HS 3
#define D_H1 2

// ws float offsets (cross-block-mutable data accessed ONLY via sc1 atomics)
#define HS_OFF 0                    // ring: 3 x 32768 floats
#define H1R_OFF 98304               // ring: 2 x 32768 floats
#define PROG_OFF 163840             // 128 gnn progress lines, stride 32 u32
#define MF_OFF   (163840 + 4096)    // 64 mlp progress lines, stride 32 u32

// GNN-block LDS (floats)
#define STH_L 0      // [2][128] own h rows (persist across phases)
#define STM_L 256    // [2][128] combined m rows
#define PT_L  512    // [8][2][128] gather partials
// MLP-block LDS (floats)
#define TGT_L 0
#define PTM_L 2048
#define PT3_L 10240
#define HC_L  11264
#define CT_L  11776
#define CZ_L  12032
#define W2_L  12288
#define HP_L  12544
#define PART_L 12800
#define ANC_L 13312
#define LP_L  13344
#define LDS_FLOATS 13360

// ---- device-coherent access (relaxed agent atomics -> sc1, bypass L1/L2) ----
__device__ __forceinline__ float2 ldc_f2(const float* p) {
    unsigned long long u = __hip_atomic_load((const unsigned long long*)p,
                                             __ATOMIC_RELAXED, __HIP_MEMORY_SCOPE_AGENT);
    float2 r;
    r.x = __uint_as_float((unsigned)u);
    r.y = __uint_as_float((unsigned)(u >> 32));
    return r;
}
__device__ __forceinline__ void stc_f(float* p, float v) {
    __hip_atomic_store((unsigned*)p, __float_as_uint(v),
                       __ATOMIC_RELAXED, __HIP_MEMORY_SCOPE_AGENT);
}
__device__ __forceinline__ unsigned ldf(const unsigned* p) {
    return __hip_atomic_load(p, __ATOMIC_RELAXED, __HIP_MEMORY_SCOPE_AGENT);
}
__device__ __forceinline__ void stf(unsigned* p, unsigned v) {
    __hip_atomic_store(p, v, __ATOMIC_RELAXED, __HIP_MEMORY_SCOPE_AGENT);
}

// block barrier that does NOT drain vmcnt
__device__ __forceinline__ void bar_lds() {
    asm volatile("s_waitcnt lgkmcnt(0)\n\ts_barrier" ::: "memory");
}

#define ISS(i) \
    float2 va##i, vb##i, vc##i, vd##i; \
    if ((i) < nst) { \
        const float* p_ = gsrc + (i) * 32 * HD; \
        if ((un >> (4 * (i)    )) & 1u) va##i = ldc_f2(p_); \
        if ((un >> (4 * (i) + 1)) & 1u) vb##i = ldc_f2(p_ + HD); \
        if ((un >> (4 * (i) + 2)) & 1u) vc##i = ldc_f2(p_ + 2 * HD); \
        if ((un >> (4 * (i) + 3)) & 1u) vd##i = ldc_f2(p_ + 3 * HD); \
    }
#define ACCP(v, b) { \
    const float f0_ = (float)((s0 >> (b)) & 1u); \
    const float f1_ = (float)((s1 >> (b)) & 1u); \
    m0.x = fmaf(f0_, v.x, m0.x); m0.y = fmaf(f0_, v.y, m0.y); \
    m1.x = fmaf(f1_, v.x, m1.x); m1.y = fmaf(f1_, v.y, m1.y); }
#define ACC1(v, b) if ((un >> (b)) & 1u) { ACCP(v, b) }
#define CNS(i) if ((i) < nst) { ACC1(va##i, 4*(i)) ACC1(vb##i, 4*(i)+1) \
                                ACC1(vc##i, 4*(i)+2) ACC1(vd##i, 4*(i)+3) }

// One GNN layer for rows {R0, R0+1}. h rows in STH (LDS), masks in scalar regs,
// gather sc1 direct-to-register; matvec col-per-lane with shuffle k-reduce.
__device__ __forceinline__ void layer(const float* src, float* dst, float bc,
    const float* z, const float* pos_emb, float* lds,
    const float (&wsA)[32], const float (&wnA)[32],
    unsigned mk0, unsigned mk1,
    int R0, int rmax, int tgate, int tnew, int lane, int wv, int tid, int c, int kbase)
{
    const int rmaxblk = min(rmax, R0 + 1);
    const int nst = (rmaxblk + 31) >> 5;  // chunks covering parent rows
    const unsigned s0 = (R0     < tgate) ? mk0 : 0u;
    const unsigned s1 = (R0 + 1 < tgate) ? mk1 : 0u;
    const unsigned un = s0 | s1;

    // new node: h row := z + pos_emb[tnew]
    if (tnew >= R0 && tnew < R0 + 2) {
        const int dr = tnew - R0;
        if (tid < HD) lds[STH_L + dr * HD + tid] = z[tid] + pos_emb[tnew * HD + tid];
    }

    // gather: wave wv owns src rows {32c' + 4wv + ss}; masked loads all in flight
    const float* gsrc = src + wv * 4 * HD + 2 * lane;
    float2 m0 = make_float2(0.f, 0.f), m1 = m0;
    ISS(0) ISS(1) ISS(2) ISS(3) ISS(4) ISS(5) ISS(6) ISS(7)
    CNS(0) CNS(1) CNS(2) CNS(3) CNS(4) CNS(5) CNS(6) CNS(7)

    // publish m partials
    float* pt = lds + PT_L + (wv * 2) * HD + 2 * lane;
    *(float2*)pt = m0;
    *(float2*)(pt + HD) = m1;
    bar_lds();
    // combine partials -> STM (2 rows x 128 k, threads 0..255)
    if (tid < 256) {
        const int dr = tid >> 7, k = tid & 127;
        float s = 0.f;
#pragma unroll
        for (int w = 0; w < 8; ++w) s += lds[PT_L + (w * 2 + dr) * HD + k];
        lds[STM_L + dr * HD + k] = s;
    }
    bar_lds();
    // matvec: lane accumulates its col over its 32-k slice, butterfly k-reduce
    float acc0 = 0.f, acc1 = 0.f;
#pragma unroll
    for (int q = 0; q < 8; ++q) {
        const float4 h0 = *(const float4*)(lds + STH_L + kbase + 4 * q);
        const float4 mm0 = *(const float4*)(lds + STM_L + kbase + 4 * q);
        const float4 h1 = *(const float4*)(lds + STH_L + HD + kbase + 4 * q);
        const float4 mm1 = *(const float4*)(lds + STM_L + HD + kbase + 4 * q);
        acc0 = fmaf(h0.x, wsA[4*q],   fmaf(mm0.x, wnA[4*q],   acc0));
        acc0 = fmaf(h0.y, wsA[4*q+1], fmaf(mm0.y, wnA[4*q+1], acc0));
        acc0 = fmaf(h0.z, wsA[4*q+2], fmaf(mm0.z, wnA[4*q+2], acc0));
        acc0 = fmaf(h0.w, wsA[4*q+3], fmaf(mm0.w, wnA[4*q+3], acc0));
        acc1 = fmaf(h1.x, wsA[4*q],   fmaf(mm1.x, wnA[4*q],   acc1));
        acc1 = fmaf(h1.y, wsA[4*q+1], fmaf(mm1.y, wnA[4*q+1], acc1));
        acc1 = fmaf(h1.z, wsA[4*q+2], fmaf(mm1.z, wnA[4*q+2], acc1));
        acc1 = fmaf(h1.w, wsA[4*q+3], fmaf(mm1.w, wnA[4*q+3], acc1));
    }
    acc0 += __shfl_xor(acc0, 16); acc0 += __shfl_xor(acc0, 32);
    acc1 += __shfl_xor(acc1, 16); acc1 += __shfl_xor(acc1, 32);
    const float o0 = fmaxf(acc0 + bc, 0.f);
    const float o1 = fmaxf(acc1 + bc, 0.f);
    // store + STH update, parallel across the 4 k-groups (all lanes hold both sums)
    const int kg = lane >> 4;
    if (kg == 0) { if (R0     <= rmaxblk) stc_f(dst + R0 * HD + c, o0); }
    else if (kg == 1) { if (R0 + 1 <= rmaxblk) stc_f(dst + (R0 + 1) * HD + c, o1); }
    else if (kg == 2) lds[STH_L + c] = o0;
    else              lds[STH_L + HD + c] = o1;
}

// ---- MLP helpers (proven numerics) ----
__device__ __forceinline__ void ct_calc(const float* hsP, const float* pos_emb,
                                        const float* Wm1, float* lds, int s)
{
    const int tid = threadIdx.x;
    if (tid < 64) {
        const float2 v = ldc_f2(hsP + s * HD + 2 * tid);
        lds[HP_L + 2 * tid] = v.x; lds[HP_L + 2 * tid + 1] = v.y;
    } else if (tid < 128) {
        const int l2 = tid - 64;
        lds[HP_L + 128 + 2 * l2]     = pos_emb[s * HD + 2 * l2];
        lds[HP_L + 128 + 2 * l2 + 1] = pos_emb[s * HD + 2 * l2 + 1];
    }
    __syncthreads();
    const int c = tid & 255, half = tid >> 8;
    float acc = 0.f;
    const float* w = half ? (Wm1 + 384 * 256 + c) : (Wm1 + c);
    const float* hh = lds + HP_L + half * 128;
#pragma unroll 4
    for (int k = 0; k < HD; ++k) acc = fmaf(hh[k], w[k * 256], acc);
    lds[PART_L + half * 256 + c] = acc;
    __syncthreads();
    if (tid < 256)
        lds[CT_L + tid] = lds[CZ_L + tid] + lds[PART_L + tid] + lds[PART_L + 256 + tid];
}

__device__ __forceinline__ void mlp_step(const float* hsP, const float* bm2,
                                         const float4 (&wm)[16], float* lds, int mb, int s)
{
    const int tid = threadIdx.x, lane = tid & 63, wv = tid >> 6;
    const int ks = wv * 16;
    if (wv < 4) {
        const int i = 4 * mb + wv;
        float2 v = make_float2(0.f, 0.f);
        if (i < s) v = ldc_f2(hsP + i * HD + 2 * lane);
        *(float2*)(lds + HC_L + wv * HD + 2 * lane) = v;
    }
    __syncthreads();
    float4 a0 = make_float4(0.f, 0.f, 0.f, 0.f), a1 = a0, a2 = a0, a3 = a0;
#pragma unroll
    for (int kk = 0; kk < 16; ++kk) {
        const int k = ks + kk;
        const float h0 = lds[HC_L + 0 * HD + k];
        const float h1 = lds[HC_L + 1 * HD + k];
        const float h2 = lds[HC_L + 2 * HD + k];
        const float h3 = lds[HC_L + 3 * HD + k];
        const float4 w = wm[kk];
        a0.x = fmaf(h0, w.x, a0.x); a0.y = fmaf(h0, w.y, a0.y);
        a0.z = fmaf(h0, w.z, a0.z); a0.w = fmaf(h0, w.w, a0.w);
        a1.x = fmaf(h1, w.x, a1.x); a1.y = fmaf(h1, w.y, a1.y);
        a1.z = fmaf(h1, w.z, a1.z); a1.w = fmaf(h1, w.w, a1.w);
        a2.x = fmaf(h2, w.x, a2.x); a2.y = fmaf(h2, w.y, a2.y);
        a2.z = fmaf(h2, w.z, a2.z); a2.w = fmaf(h2, w.w, a2.w);
        a3.x = fmaf(h3, w.x, a3.x); a3.y = fmaf(h3, w.y, a3.y);
        a3.z = fmaf(h3, w.z, a3.z); a3.w = fmaf(h3, w.w, a3.w);
    }
    *(float4*)(lds + PTM_L + (wv * 4 + 0) * 256 + 4 * lane) = a0;
    *(float4*)(lds + PTM_L + (wv * 4 + 1) * 256 + 4 * lane) = a1;
    *(float4*)(lds + PTM_L + (wv * 4 + 2) * 256 + 4 * lane) = a2;
    *(float4*)(lds + PTM_L + (wv * 4 + 3) * 256 + 4 * lane) = a3;
    __syncthreads();
    {
        const int c = tid & 255, ci2 = (tid >> 8) * 2;
#pragma unroll
        for (int q = 0; q < 2; ++q) {
            const int ci = ci2 + q;
            float v = lds[CT_L + c];
#pragma unroll
            for (int w = 0; w < 8; ++w) v += lds[PTM_L + (w * 4 + ci) * 256 + c];
            lds[PT3_L + ci * 256 + c] = fmaxf(v, 0.f) * lds[W2_L + c];
        }
    }
    __syncthreads();
    if (wv < 4) {
        const int ci = wv, i = 4 * mb + ci;
        if (i < s) {
            float sd = lds[PT3_L + ci * 256 + lane] + lds[PT3_L + ci * 256 + 64 + lane]
                     + lds[PT3_L + ci * 256 + 128 + lane] + lds[PT3_L + ci * 256 + 192 + lane];
#pragma unroll
            for (int off = 32; off > 0; off >>= 1) sd += __shfl_xor(sd, off);
            if (lane == 0) {
                const unsigned* gtl = (const unsigned*)(lds + TGT_L) + s * 8;
                unsigned* ancl = (unsigned*)(lds + ANC_L);
                const float logit = sd + bm2[0];
                const float prob = 1.f / (1.f + expf(-logit));
                unsigned cnt = 0, has = 0;
#pragma unroll
                for (int w = 0; w < 8; ++w) {
                    const unsigned av = ancl[ci * 8 + w];
                    cnt += __popc(av);
                    has |= av & gtl[w];
                }
                const float supp = ldexpf(1.f, -(int)cnt);  // 0.5^cnt exact
                const float adj = prob * supp;
                const unsigned gt = (gtl[i >> 5] >> (i & 31)) & 1u;
                const float lpv = gt ? logf(adj + 1e-12f) : logf(1.f - adj + 1e-12f);
                atomicAdd((float*)(lds + LP_L), lpv);
                if (has | gt) ancl[ci * 8 + (s >> 5)] |= (1u << (s & 31));
            }
        }
    }
}

extern "C" __global__ void __launch_bounds__(NTHR)
fused_gnn(const float* z, const int* targets, const float* pos_emb,
          const float* Ws1, const float* Wn1, const float* b1,
          const float* Ws2, const float* Wn2, const float* b2,
          const float* Wm1, const float* bm1, const float* Wm2, const float* bm2,
          const float* Wf, const float* bf, float* out, float* ws)
{
    __shared__ __align__(16) float lds[LDS_FLOATS];
    const int b = blockIdx.x;
    const int tid = threadIdx.x, lane = tid & 63, wv = tid >> 6;

    unsigned* prog = (unsigned*)(ws + PROG_OFF);
    unsigned* mf   = (unsigned*)(ws + MF_OFF);
    float* lp_out = out + NN * NN + NN * 16;

    if (b < GNN_NB) {
        const int R0 = b * 2;
        const int c = 16 * wv + (lane & 15);     // this lane's output column
        const int kbase = 32 * (lane >> 4);      // this lane's k-slice
        // weights into registers (both layers): w[i] = W[(kbase+i)][c]
        float ws1[32], wn1[32], ws2[32], wn2[32];
#pragma unroll
        for (int i = 0; i < 32; ++i) {
            ws1[i] = Ws1[(kbase + i) * HD + c];
            wn1[i] = Wn1[(kbase + i) * HD + c];
            ws2[i] = Ws2[(kbase + i) * HD + c];
            wn2[i] = Wn2[(kbase + i) * HD + c];
        }
        const float b1c = b1[c], b2c = b2[c];
        // per-wave static gather masks: bit bb <-> src row (bb>>2)*32 + 4wv + (bb&3)
        unsigned mk0, mk1;
        {
            const int srcl = (lane < 32) ? (((lane >> 2) << 5) + wv * 4 + (lane & 3)) : 0;
#define BALLOT_MK(dr, dst) { \
            const int r_ = R0 + (dr); \
            const bool p_ = (lane < 32) && (srcl < r_) && (targets[r_ * NN + srcl] != 0); \
            const unsigned long long bm_ = __ballot(p_); \
            dst = (unsigned)__builtin_amdgcn_readfirstlane((int)(unsigned)bm_); }
            BALLOT_MK(0, mk0) BALLOT_MK(1, mk1)
#undef BALLOT_MK
        }
        // init: STH rows, Hs(0) slot 0, tgt output
        if (tid < 256) lds[STH_L + tid] = (b == 0 && tid < HD) ? z[tid] : 0.f;
        if (tid < 256) {
            const int dr = tid >> 7, cc = tid & 127, r = R0 + dr;
            stc_f(ws + HS_OFF + r * HD + cc, (r == 0) ? z[cc] : 0.f);
        }
        if (wv < 2) {
            const int r = R0 + wv;
            const int4 tv = ((const int4*)(targets + r * NN))[lane];
            float4 ov;
            ov.x = (4 * lane     < r) ? (float)tv.x : 0.f;
            ov.y = (4 * lane + 1 < r) ? (float)tv.y : 0.f;
            ov.z = (4 * lane + 2 < r) ? (float)tv.z : 0.f;
            ov.w = (4 * lane + 3 < r) ? (float)tv.w : 0.f;
            ((float4*)(out + r * NN))[lane] = ov;
        }
        __syncthreads();  // drain init stores
        if (tid == 0) stf(prog + b * 32, 1u);

        // monotone flag caches (registers): poll only when cache < threshold
        unsigned seenP = 0;   // tid < GNN_NB: cached prog[tid]
        int      seenM = 0;   // tid in [GNN_NB, GNN_NB+MLP_NB): cached mf[tid-GNN_NB]

        for (int t = 1; t <= 256; ++t) {
            const float* hsP = ws + HS_OFF + ((t - 1) % D_HS) * 32768;
            float* h1c = ws + H1R_OFF + (t & 1) * 32768;        // t % D_H1
            float* hsN = ws + HS_OFF + (t % D_HS) * 32768;
            const int rmax  = (t <= 255) ? t : 255;
            const int tgate = (t <= 255) ? t : 300;
            const int tnew  = (t <= 255) ? t : -1;
            const bool act = (R0 <= rmax);

            // layer1(t): data b'<b >= 2t-1; H1 ring (occupant t-2): all >= 2(t-2)+1
            if (act) {
                {
                    const unsigned dataTh = 2u * t - 1u;
                    const unsigned ringTh = (t > D_H1) ? (2u * (t - D_H1) + 1u) : 0u;
                    if (tid < GNN_NB) {
                        const unsigned th = (tid < b) ? dataTh : ringTh;
                        if (seenP < th) {
                            unsigned v;
                            for (;;) {
                                v = ldf(prog + tid * 32);
                                if (v >= th) break;
                                __builtin_amdgcn_s_sleep(1);
                            }
                            seenP = v;
                        }
                    }
                    __syncthreads();
                    asm volatile("" ::: "memory");
                }
                layer(hsP, h1c, b1c, z, pos_emb, lds, ws1, wn1,
                      mk0, mk1, R0, rmax, tgate, tnew, lane, wv, tid, c, kbase);
            }
            __syncthreads();
            if (tid == 0) stf(prog + b * 32, 2u * t);

            // layer2(t): data b'<b >= 2t; Hs ring (occupant t-3): all >= 2(t-2),
            // and MLP(t-3) done with Hs(t-3)
            if (act) {
                {
                    const unsigned dataTh = 2u * t;
                    const unsigned ringTh = (t > D_HS) ? (2u * (t - D_HS + 1)) : 0u;
                    const int mlpTh = t - D_HS;
                    if (tid < GNN_NB) {
                        const unsigned th = (tid < b) ? dataTh : ringTh;
                        if (seenP < th) {
                            unsigned v;
                            for (;;) {
                                v = ldf(prog + tid * 32);
                                if (v >= th) break;
                                __builtin_amdgcn_s_sleep(1);
                            }
                            seenP = v;
                        }
                    } else if (tid < GNN_NB + MLP_NB) {
                        if (mlpTh > 0 && seenM < mlpTh) {
                            int v;
                            for (;;) {
                                v = (int)ldf(mf + (tid - GNN_NB) * 32);
                                if (v >= mlpTh) break;
                                __builtin_amdgcn_s_sleep(1);
                            }
                            seenM = v;
                        }
                    }
                    __syncthreads();
                    asm volatile("" ::: "memory");
                }
                layer(h1c, hsN, b2c, z, pos_emb, lds, ws2, wn2,
                      mk0, mk1, R0, rmax, tgate, -1, lane, wv, tid, c, kbase);
            }
            __syncthreads();
            if (tid == 0) stf(prog + b * 32, 2u * t + 1u);
        }

        // X_out from STH (final Hs rows of this block)
        if (wv < 2) {
            const int r = R0 + wv;
            const float* strow = lds + STH_L + wv * HD;
            const int f = lane & 15, kp = lane >> 4;
            float sacc = 0.f;
#pragma unroll
            for (int k = 0; k < 32; ++k)
                sacc = fmaf(strow[kp * 32 + k], Wf[(kp * 32 + k) * 16 + f], sacc);
            sacc += __shfl_xor(sacc, 16);
            sacc += __shfl_xor(sacc, 32);
            if (lane < 16) out[NN * NN + r * 16 + f] = sacc + bf[f];
        }
    } else {
        // ---- MLP block: trails the GNN via prog counters ----
        const int mb = b - GNN_NB;
        const int ks = wv * 16;
        float4 wm[16];
#pragma unroll
        for (int kk = 0; kk < 16; ++kk)
            wm[kk] = *(const float4*)(Wm1 + (128 + ks + kk) * 256 + 4 * lane);
        {
            unsigned* tg = (unsigned*)(lds + TGT_L);
            for (int rr = 0; rr < 32; ++rr) {
                const int r = wv * 32 + rr;
#pragma unroll
                for (int q = 0; q < 4; ++q) {
                    const int j = q * 64 + lane;
                    const unsigned long long bm = __ballot(j < r && targets[r * NN + j] != 0);
                    if (lane == 0) {
                        tg[r * 8 + 2 * q]     = (unsigned)bm;
                        tg[r * 8 + 2 * q + 1] = (unsigned)(bm >> 32);
                    }
                }
            }
        }
        if (tid < 256) {
            lds[W2_L + tid] = Wm2[tid];
            float acc = bm1[tid];
            for (int k = 0; k < HD; ++k) acc = fmaf(z[k], Wm1[(256 + k) * 256 + tid], acc);
            lds[CZ_L + tid] = acc;
        }
        if (tid < 32) ((unsigned*)(lds + ANC_L))[tid] = 0u;
        if (tid == 0) lds[LP_L] = 0.f;

        unsigned seenP = 0;  // tid < GNN_NB: cached prog[tid]
        for (int s = 1; s <= 255; ++s) {
            // Hs(s) complete <=> all gnn prog >= 2s+1
            if (tid < GNN_NB) {
                const unsigned need = 2u * (unsigned)s + 1u;
                if (seenP < need) {
                    unsigned v;
                    for (;;) {
                        v = ldf(prog + tid * 32);
                        if (v >= need) break;
                        __builtin_amdgcn_s_sleep(1);
                    }
                    seenP = v;
                }
            }
            __syncthreads();
            const float* hsP = ws + HS_OFF + (s % D_HS) * 32768;
            if (4 * mb < s) {
                ct_calc(hsP, pos_emb, Wm1, lds, s);
                __syncthreads();
                mlp_step(hsP, bm2, wm, lds, mb, s);
            }
            __syncthreads();  // all reads of Hs(s) done (vmcnt drained per wave)
            if (tid == 0) stf(mf + mb * 32, (unsigned)s);
        }
        __syncthreads();
        if (tid == 0) atomicAdd(lp_out, lds[LP_L]);
    }
}

extern "C" void kernel_launch(void* const* d_in, const int* in_sizes, int n_in,
                              void* d_out, int out_size, void* d_ws, size_t ws_size,
                              hipStream_t stream)
{
    const float* z       = (const float*)d_in[0];
    const int*   targets = (const int*)d_in[1];
    const float* pos_emb = (const float*)d_in[2];
    const float* Ws1     = (const float*)d_in[3];
    const float* Wn1     = (const float*)d_in[4];
    const float* b1      = (const float*)d_in[5];
    const float* Ws2     = (const float*)d_in[6];
    const float* Wn2     = (const float*)d_in[7];
    const float* b2      = (const float*)d_in[8];
    const float* Wm1     = (const float*)d_in[9];
    const float* bm1     = (const float*)d_in[10];
    const float* Wm2     = (const float*)d_in[11];
    const float* bm2     = (const float*)d_in[12];
    const float* Wf      = (const float*)d_in[13];
    const float* bf      = (const float*)d_in[14];
    float* out = (float*)d_out;
    float* ws  = (float*)d_ws;

    // zero prog + mf flag lines and the lp accumulator each call
    (void)hipMemsetAsync(ws + PROG_OFF, 0, (GNN_NB + MLP_NB) * 32 * sizeof(unsigned), stream);
    (void)hipMemsetAsync(out + NN * NN + NN * 16, 0, sizeof(float), stream);

    void* args[17] = {
        (void*)&z, (void*)&targets, (void*)&pos_emb,
        (void*)&Ws1, (void*)&Wn1, (void*)&b1,
        (void*)&Ws2, (void*)&Wn2, (void*)&b2,
        (void*)&Wm1, (void*)&bm1, (void*)&Wm2, (void*)&bm2,
        (void*)&Wf, (void*)&bf, (void*)&out, (void*)&ws
    };
    (void)hipLaunchCooperativeKernel((const void*)fused_gnn, dim3(NBLK), dim3(NTHR),
                                     args, 0, stream);
}

// Round 13
// 1797.559 us; speedup vs baseline: 1.6114x; 1.0114x over previous
//
#include <hip/hip_runtime.h>

#define NN 256
#define HD 128
#define GNN_NB 128
#define MLP_NB 64
#define NBLK 192
#define NTHR 512
#define D_HS 3
#define D_H1 2

// ws float offsets (cross-block-mutable data accessed ONLY via sc1 atomics)
#define HS_OFF 0                    // ring: 3 x 32768 floats
#define H1R_OFF 98304               // ring: 2 x 32768 floats
#define PROG_OFF 163840             // 128 gnn progress lines, stride 32 u32
#define MF_OFF   (163840 + 4096)    // 64 mlp progress lines, stride 32 u32

// GNN-block LDS (floats)
#define STH_L 0      // [2][128] own h rows (persist across phases)
#define STM_L 256    // [2][128] combined m rows
#define PT_L  512    // [8][2][128] gather partials
// MLP-block LDS (floats)
#define TGT_L 0
#define PTM_L 2048
#define PT3_L 10240
#define HC_L  11264
#define CT_L  11776
#define CZ_L  12032
#define W2_L  12288
#define HP_L  12544
#define PART_L 12800
#define ANC_L 13312
#define LP_L  13344
#define LDS_FLOATS 13360

// ---- device-coherent access (relaxed agent atomics -> sc1, bypass L1/L2) ----
__device__ __forceinline__ float2 ldc_f2(const float* p) {
    unsigned long long u = __hip_atomic_load((const unsigned long long*)p,
                                             __ATOMIC_RELAXED, __HIP_MEMORY_SCOPE_AGENT);
    float2 r;
    r.x = __uint_as_float((unsigned)u);
    r.y = __uint_as_float((unsigned)(u >> 32));
    return r;
}
__device__ __forceinline__ void stc_f(float* p, float v) {
    __hip_atomic_store((unsigned*)p, __float_as_uint(v),
                       __ATOMIC_RELAXED, __HIP_MEMORY_SCOPE_AGENT);
}
__device__ __forceinline__ unsigned ldf(const unsigned* p) {
    return __hip_atomic_load(p, __ATOMIC_RELAXED, __HIP_MEMORY_SCOPE_AGENT);
}
__device__ __forceinline__ void stf(unsigned* p, unsigned v) {
    __hip_atomic_store(p, v, __ATOMIC_RELAXED, __HIP_MEMORY_SCOPE_AGENT);
}

// block barrier that does NOT drain vmcnt
__device__ __forceinline__ void bar_lds() {
    asm volatile("s_waitcnt lgkmcnt(0)\n\ts_barrier" ::: "memory");
}

#define ISS(i) \
    float2 va##i, vb##i, vc##i, vd##i; \
    if ((i) < nst) { \
        const float* p_ = gsrc + (i) * 32 * HD; \
        if ((un >> (4 * (i)    )) & 1u) va##i = ldc_f2(p_); \
        if ((un >> (4 * (i) + 1)) & 1u) vb##i = ldc_f2(p_ + HD); \
        if ((un >> (4 * (i) + 2)) & 1u) vc##i = ldc_f2(p_ + 2 * HD); \
        if ((un >> (4 * (i) + 3)) & 1u) vd##i = ldc_f2(p_ + 3 * HD); \
    }
#define ACCP(v, b) { \
    const float f0_ = (float)((s0 >> (b)) & 1u); \
    const float f1_ = (float)((s1 >> (b)) & 1u); \
    m0.x = fmaf(f0_, v.x, m0.x); m0.y = fmaf(f0_, v.y, m0.y); \
    m1.x = fmaf(f1_, v.x, m1.x); m1.y = fmaf(f1_, v.y, m1.y); }
#define ACC1(v, b) if ((un >> (b)) & 1u) { ACCP(v, b) }
#define CNS(i) if ((i) < nst) { ACC1(va##i, 4*(i)) ACC1(vb##i, 4*(i)+1) \
                                ACC1(vc##i, 4*(i)+2) ACC1(vd##i, 4*(i)+3) }

// One GNN layer for rows {R0, R0+1}. h rows in STH (LDS), masks in scalar regs,
// gather sc1 direct-to-register; matvec col-per-lane with shuffle k-reduce.
__device__ __forceinline__ void layer(const float* src, float* dst, float bc,
    const float* z, const float* pos_emb, float* lds,
    const float (&wsA)[32], const float (&wnA)[32],
    unsigned mk0, unsigned mk1,
    int R0, int rmax, int tgate, int tnew, int lane, int wv, int tid, int c, int kbase)
{
    const int rmaxblk = min(rmax, R0 + 1);
    const int nst = (rmaxblk + 31) >> 5;  // chunks covering parent rows
    const unsigned s0 = (R0     < tgate) ? mk0 : 0u;
    const unsigned s1 = (R0 + 1 < tgate) ? mk1 : 0u;
    const unsigned un = s0 | s1;

    // new node: h row := z + pos_emb[tnew]
    if (tnew >= R0 && tnew < R0 + 2) {
        const int dr = tnew - R0;
        if (tid < HD) lds[STH_L + dr * HD + tid] = z[tid] + pos_emb[tnew * HD + tid];
    }

    // gather: wave wv owns src rows {32c' + 4wv + ss}; masked loads all in flight
    const float* gsrc = src + wv * 4 * HD + 2 * lane;
    float2 m0 = make_float2(0.f, 0.f), m1 = m0;
    ISS(0) ISS(1) ISS(2) ISS(3) ISS(4) ISS(5) ISS(6) ISS(7)
    CNS(0) CNS(1) CNS(2) CNS(3) CNS(4) CNS(5) CNS(6) CNS(7)

    // publish m partials
    float* pt = lds + PT_L + (wv * 2) * HD + 2 * lane;
    *(float2*)pt = m0;
    *(float2*)(pt + HD) = m1;
    bar_lds();
    // combine partials -> STM (2 rows x 128 k, threads 0..255)
    if (tid < 256) {
        const int dr = tid >> 7, k = tid & 127;
        float s = 0.f;
#pragma unroll
        for (int w = 0; w < 8; ++w) s += lds[PT_L + (w * 2 + dr) * HD + k];
        lds[STM_L + dr * HD + k] = s;
    }
    bar_lds();
    // matvec: lane accumulates its col over its 32-k slice, butterfly k-reduce
    float acc0 = 0.f, acc1 = 0.f;
#pragma unroll
    for (int q = 0; q < 8; ++q) {
        const float4 h0 = *(const float4*)(lds + STH_L + kbase + 4 * q);
        const float4 mm0 = *(const float4*)(lds + STM_L + kbase + 4 * q);
        const float4 h1 = *(const float4*)(lds + STH_L + HD + kbase + 4 * q);
        const float4 mm1 = *(const float4*)(lds + STM_L + HD + kbase + 4 * q);
        acc0 = fmaf(h0.x, wsA[4*q],   fmaf(mm0.x, wnA[4*q],   acc0));
        acc0 = fmaf(h0.y, wsA[4*q+1], fmaf(mm0.y, wnA[4*q+1], acc0));
        acc0 = fmaf(h0.z, wsA[4*q+2], fmaf(mm0.z, wnA[4*q+2], acc0));
        acc0 = fmaf(h0.w, wsA[4*q+3], fmaf(mm0.w, wnA[4*q+3], acc0));
        acc1 = fmaf(h1.x, wsA[4*q],   fmaf(mm1.x, wnA[4*q],   acc1));
        acc1 = fmaf(h1.y, wsA[4*q+1], fmaf(mm1.y, wnA[4*q+1], acc1));
        acc1 = fmaf(h1.z, wsA[4*q+2], fmaf(mm1.z, wnA[4*q+2], acc1));
        acc1 = fmaf(h1.w, wsA[4*q+3], fmaf(mm1.w, wnA[4*q+3], acc1));
    }
    acc0 += __shfl_xor(acc0, 16); acc0 += __shfl_xor(acc0, 32);
    acc1 += __shfl_xor(acc1, 16); acc1 += __shfl_xor(acc1, 32);
    const float o0 = fmaxf(acc0 + bc, 0.f);
    const float o1 = fmaxf(acc1 + bc, 0.f);
    // store + STH update, parallel across the 4 k-groups (all lanes hold both sums)
    const int kg = lane >> 4;
    if (kg == 0) { if (R0     <= rmaxblk) stc_f(dst + R0 * HD + c, o0); }
    else if (kg == 1) { if (R0 + 1 <= rmaxblk) stc_f(dst + (R0 + 1) * HD + c, o1); }
    else if (kg == 2) lds[STH_L + c] = o0;
    else              lds[STH_L + HD + c] = o1;
}

// ---- MLP helpers (proven numerics) ----
__device__ __forceinline__ void ct_calc(const float* hsP, const float* pos_emb,
                                        const float* Wm1, float* lds, int s)
{
    const int tid = threadIdx.x;
    if (tid < 64) {
        const float2 v = ldc_f2(hsP + s * HD + 2 * tid);
        lds[HP_L + 2 * tid] = v.x; lds[HP_L + 2 * tid + 1] = v.y;
    } else if (tid < 128) {
        const int l2 = tid - 64;
        lds[HP_L + 128 + 2 * l2]     = pos_emb[s * HD + 2 * l2];
        lds[HP_L + 128 + 2 * l2 + 1] = pos_emb[s * HD + 2 * l2 + 1];
    }
    __syncthreads();
    const int c = tid & 255, half = tid >> 8;
    float acc = 0.f;
    const float* w = half ? (Wm1 + 384 * 256 + c) : (Wm1 + c);
    const float* hh = lds + HP_L + half * 128;
#pragma unroll 4
    for (int k = 0; k < HD; ++k) acc = fmaf(hh[k], w[k * 256], acc);
    lds[PART_L + half * 256 + c] = acc;
    __syncthreads();
    if (tid < 256)
        lds[CT_L + tid] = lds[CZ_L + tid] + lds[PART_L + tid] + lds[PART_L + 256 + tid];
}

__device__ __forceinline__ void mlp_step(const float* hsP, const float* bm2,
                                         const float4 (&wm)[16], float* lds, int mb, int s)
{
    const int tid = threadIdx.x, lane = tid & 63, wv = tid >> 6;
    const int ks = wv * 16;
    if (wv < 4) {
        const int i = 4 * mb + wv;
        float2 v = make_float2(0.f, 0.f);
        if (i < s) v = ldc_f2(hsP + i * HD + 2 * lane);
        *(float2*)(lds + HC_L + wv * HD + 2 * lane) = v;
    }
    __syncthreads();
    float4 a0 = make_float4(0.f, 0.f, 0.f, 0.f), a1 = a0, a2 = a0, a3 = a0;
#pragma unroll
    for (int kk = 0; kk < 16; ++kk) {
        const int k = ks + kk;
        const float h0 = lds[HC_L + 0 * HD + k];
        const float h1 = lds[HC_L + 1 * HD + k];
        const float h2 = lds[HC_L + 2 * HD + k];
        const float h3 = lds[HC_L + 3 * HD + k];
        const float4 w = wm[kk];
        a0.x = fmaf(h0, w.x, a0.x); a0.y = fmaf(h0, w.y, a0.y);
        a0.z = fmaf(h0, w.z, a0.z); a0.w = fmaf(h0, w.w, a0.w);
        a1.x = fmaf(h1, w.x, a1.x); a1.y = fmaf(h1, w.y, a1.y);
        a1.z = fmaf(h1, w.z, a1.z); a1.w = fmaf(h1, w.w, a1.w);
        a2.x = fmaf(h2, w.x, a2.x); a2.y = fmaf(h2, w.y, a2.y);
        a2.z = fmaf(h2, w.z, a2.z); a2.w = fmaf(h2, w.w, a2.w);
        a3.x = fmaf(h3, w.x, a3.x); a3.y = fmaf(h3, w.y, a3.y);
        a3.z = fmaf(h3, w.z, a3.z); a3.w = fmaf(h3, w.w, a3.w);
    }
    *(float4*)(lds + PTM_L + (wv * 4 + 0) * 256 + 4 * lane) = a0;
    *(float4*)(lds + PTM_L + (wv * 4 + 1) * 256 + 4 * lane) = a1;
    *(float4*)(lds + PTM_L + (wv * 4 + 2) * 256 + 4 * lane) = a2;
    *(float4*)(lds + PTM_L + (wv * 4 + 3) * 256 + 4 * lane) = a3;
    __syncthreads();
    {
        const int c = tid & 255, ci2 = (tid >> 8) * 2;
#pragma unroll
        for (int q = 0; q < 2; ++q) {
            const int ci = ci2 + q;
            float v = lds[CT_L + c];
#pragma unroll
            for (int w = 0; w < 8; ++w) v += lds[PTM_L + (w * 4 + ci) * 256 + c];
            lds[PT3_L + ci * 256 + c] = fmaxf(v, 0.f) * lds[W2_L + c];
        }
    }
    __syncthreads();
    if (wv < 4) {
        const int ci = wv, i = 4 * mb + ci;
        if (i < s) {
            float sd = lds[PT3_L + ci * 256 + lane] + lds[PT3_L + ci * 256 + 64 + lane]
                     + lds[PT3_L + ci * 256 + 128 + lane] + lds[PT3_L + ci * 256 + 192 + lane];
#pragma unroll
            for (int off = 32; off > 0; off >>= 1) sd += __shfl_xor(sd, off);
            if (lane == 0) {
                const unsigned* gtl = (const unsigned*)(lds + TGT_L) + s * 8;
                unsigned* ancl = (unsigned*)(lds + ANC_L);
                const float logit = sd + bm2[0];
                const float prob = 1.f / (1.f + expf(-logit));
                unsigned cnt = 0, has = 0;
#pragma unroll
                for (int w = 0; w < 8; ++w) {
                    const unsigned av = ancl[ci * 8 + w];
                    cnt += __popc(av);
                    has |= av & gtl[w];
                }
                const float supp = ldexpf(1.f, -(int)cnt);  // 0.5^cnt exact
                const float adj = prob * supp;
                const unsigned gt = (gtl[i >> 5] >> (i & 31)) & 1u;
                const float lpv = gt ? logf(adj + 1e-12f) : logf(1.f - adj + 1e-12f);
                atomicAdd((float*)(lds + LP_L), lpv);
                if (has | gt) ancl[ci * 8 + (s >> 5)] |= (1u << (s & 31));
            }
        }
    }
}

extern "C" __global__ void __launch_bounds__(NTHR)
fused_gnn(const float* z, const int* targets, const float* pos_emb,
          const float* Ws1, const float* Wn1, const float* b1,
          const float* Ws2, const float* Wn2, const float* b2,
          const float* Wm1, const float* bm1, const float* Wm2, const float* bm2,
          const float* Wf, const float* bf, float* out, float* ws)
{
    __shared__ __align__(16) float lds[LDS_FLOATS];
    const int b = blockIdx.x;
    const int tid = threadIdx.x, lane = tid & 63, wv = tid >> 6;

    unsigned* prog = (unsigned*)(ws + PROG_OFF);
    unsigned* mf   = (unsigned*)(ws + MF_OFF);
    float* lp_out = out + NN * NN + NN * 16;

    if (b < GNN_NB) {
        const int R0 = b * 2;
        const int c = 16 * wv + (lane & 15);     // this lane's output column
        const int kbase = 32 * (lane >> 4);      // this lane's k-slice
        // weights into registers (both layers): w[i] = W[(kbase+i)][c]
        float ws1[32], wn1[32], ws2[32], wn2[32];
#pragma unroll
        for (int i = 0; i < 32; ++i) {
            ws1[i] = Ws1[(kbase + i) * HD + c];
            wn1[i] = Wn1[(kbase + i) * HD + c];
            ws2[i] = Ws2[(kbase + i) * HD + c];
            wn2[i] = Wn2[(kbase + i) * HD + c];
        }
        const float b1c = b1[c], b2c = b2[c];
        // per-wave static gather masks: bit bb <-> src row (bb>>2)*32 + 4wv + (bb&3)
        unsigned mk0, mk1;
        {
            const int srcl = (lane < 32) ? (((lane >> 2) << 5) + wv * 4 + (lane & 3)) : 0;
#define BALLOT_MK(dr, dst) { \
            const int r_ = R0 + (dr); \
            const bool p_ = (lane < 32) && (srcl < r_) && (targets[r_ * NN + srcl] != 0); \
            const unsigned long long bm_ = __ballot(p_); \
            dst = (unsigned)__builtin_amdgcn_readfirstlane((int)(unsigned)bm_); }
            BALLOT_MK(0, mk0) BALLOT_MK(1, mk1)
#undef BALLOT_MK
        }
        // init: STH rows, Hs(0) slot 0, tgt output
        if (tid < 256) lds[STH_L + tid] = (b == 0 && tid < HD) ? z[tid] : 0.f;
        if (tid < 256) {
            const int dr = tid >> 7, cc = tid & 127, r = R0 + dr;
            stc_f(ws + HS_OFF + r * HD + cc, (r == 0) ? z[cc] : 0.f);
        }
        if (wv < 2) {
            const int r = R0 + wv;
            const int4 tv = ((const int4*)(targets + r * NN))[lane];
            float4 ov;
            ov.x = (4 * lane     < r) ? (float)tv.x : 0.f;
            ov.y = (4 * lane + 1 < r) ? (float)tv.y : 0.f;
            ov.z = (4 * lane + 2 < r) ? (float)tv.z : 0.f;
            ov.w = (4 * lane + 3 < r) ? (float)tv.w : 0.f;
            ((float4*)(out + r * NN))[lane] = ov;
        }
        __syncthreads();  // drain init stores
        if (tid == 0) stf(prog + b * 32, 1u);

        // monotone flag caches (registers): poll only when cache < threshold
        unsigned seenP = 0;   // tid < GNN_NB: cached prog[tid]
        int      seenM = 0;   // tid in [GNN_NB, GNN_NB+MLP_NB): cached mf[tid-GNN_NB]

        for (int t = 1; t <= 256; ++t) {
            const float* hsP = ws + HS_OFF + ((t - 1) % D_HS) * 32768;
            float* h1c = ws + H1R_OFF + (t & 1) * 32768;        // t % D_H1
            float* hsN = ws + HS_OFF + (t % D_HS) * 32768;
            const int rmax  = (t <= 255) ? t : 255;
            const int tgate = (t <= 255) ? t : 300;
            const int tnew  = (t <= 255) ? t : -1;
            const bool act = (R0 <= rmax);

            // layer1(t): data b'<b >= 2t-1; H1 ring (occupant t-2): all >= 2(t-2)+1
            if (act) {
                {
                    const unsigned dataTh = 2u * t - 1u;
                    const unsigned ringTh = (t > D_H1) ? (2u * (t - D_H1) + 1u) : 0u;
                    if (tid < GNN_NB) {
                        const unsigned th = (tid < b) ? dataTh : ringTh;
                        if (seenP < th) {
                            unsigned v;
                            for (;;) {
                                v = ldf(prog + tid * 32);
                                if (v >= th) break;
                                __builtin_amdgcn_s_sleep(1);
                            }
                            seenP = v;
                        }
                    }
                    __syncthreads();
                    asm volatile("" ::: "memory");
                }
                layer(hsP, h1c, b1c, z, pos_emb, lds, ws1, wn1,
                      mk0, mk1, R0, rmax, tgate, tnew, lane, wv, tid, c, kbase);
            }
            __syncthreads();
            if (tid == 0) stf(prog + b * 32, 2u * t);

            // layer2(t): data b'<b >= 2t; Hs ring (occupant t-D_HS, rows 2b,2b+1):
            // gnn readers covered by ringTh; MLP readers: candidate block b>>1 always,
            // ALL mlp blocks only when b owns row t-D_HS (rotating, 2x per run).
            if (act) {
                {
                    const unsigned dataTh = 2u * t;
                    const unsigned ringTh = (t > D_HS) ? (2u * (t - D_HS + 1)) : 0u;
                    const int mlpTh = t - D_HS;
                    const bool ownRow = (mlpTh > 0) && ((mlpTh >> 1) == b);
                    if (tid < GNN_NB) {
                        const unsigned th = (tid < b) ? dataTh : ringTh;
                        if (seenP < th) {
                            unsigned v;
                            for (;;) {
                                v = ldf(prog + tid * 32);
                                if (v >= th) break;
                                __builtin_amdgcn_s_sleep(1);
                            }
                            seenP = v;
                        }
                    } else if (tid < GNN_NB + MLP_NB) {
                        const int mi = tid - GNN_NB;
                        const int thm = (mlpTh > 0 && (mi == (b >> 1) || ownRow)) ? mlpTh : 0;
                        if (thm > 0 && seenM < thm) {
                            int v;
                            for (;;) {
                                v = (int)ldf(mf + mi * 32);
                                if (v >= thm) break;
                                __builtin_amdgcn_s_sleep(1);
                            }
                            seenM = v;
                        }
                    }
                    __syncthreads();
                    asm volatile("" ::: "memory");
                }
                layer(h1c, hsN, b2c, z, pos_emb, lds, ws2, wn2,
                      mk0, mk1, R0, rmax, tgate, -1, lane, wv, tid, c, kbase);
            }
            __syncthreads();
            if (tid == 0) stf(prog + b * 32, 2u * t + 1u);
        }

        // X_out from STH (final Hs rows of this block)
        if (wv < 2) {
            const int r = R0 + wv;
            const float* strow = lds + STH_L + wv * HD;
            const int f = lane & 15, kp = lane >> 4;
            float sacc = 0.f;
#pragma unroll
            for (int k = 0; k < 32; ++k)
                sacc = fmaf(strow[kp * 32 + k], Wf[(kp * 32 + k) * 16 + f], sacc);
            sacc += __shfl_xor(sacc, 16);
            sacc += __shfl_xor(sacc, 32);
            if (lane < 16) out[NN * NN + r * 16 + f] = sacc + bf[f];
        }
    } else {
        // ---- MLP block: trails producers via SPARSE prog waits ----
        const int mb = b - GNN_NB;
        const int ks = wv * 16;
        float4 wm[16];
#pragma unroll
        for (int kk = 0; kk < 16; ++kk)
            wm[kk] = *(const float4*)(Wm1 + (128 + ks + kk) * 256 + 4 * lane);
        {
            unsigned* tg = (unsigned*)(lds + TGT_L);
            for (int rr = 0; rr < 32; ++rr) {
                const int r = wv * 32 + rr;
#pragma unroll
                for (int q = 0; q < 4; ++q) {
                    const int j = q * 64 + lane;
                    const unsigned long long bm = __ballot(j < r && targets[r * NN + j] != 0);
                    if (lane == 0) {
                        tg[r * 8 + 2 * q]     = (unsigned)bm;
                        tg[r * 8 + 2 * q + 1] = (unsigned)(bm >> 32);
                    }
                }
            }
        }
        if (tid < 256) {
            lds[W2_L + tid] = Wm2[tid];
            float acc = bm1[tid];
            for (int k = 0; k < HD; ++k) acc = fmaf(z[k], Wm1[(256 + k) * 256 + tid], acc);
            lds[CZ_L + tid] = acc;
        }
        if (tid < 32) ((unsigned*)(lds + ANC_L))[tid] = 0u;
        if (tid == 0) lds[LP_L] = 0.f;

        unsigned seenP = 0;  // tid < GNN_NB: cached prog[tid]
        for (int s = 1; s <= 255; ++s) {
            // Need Hs(s) rows {4mb..4mb+3} (blocks 2mb,2mb+1) and row s (block s>>1):
            // only those 3 flags >= 2s+1; skip entirely if no candidates yet.
            if (4 * mb < s && tid < GNN_NB) {
                const bool needed = (tid == 2 * mb) || (tid == 2 * mb + 1) ||
                                    (tid == (s >> 1));
                if (needed) {
                    const unsigned need = 2u * (unsigned)s + 1u;
                    if (seenP < need) {
                        unsigned v;
                        for (;;) {
                            v = ldf(prog + tid * 32);
                            if (v >= need) break;
                            __builtin_amdgcn_s_sleep(1);
                        }
                        seenP = v;
                    }
                }
            }
            __syncthreads();
            const float* hsP = ws + HS_OFF + (s % D_HS) * 32768;
            if (4 * mb < s) {
                ct_calc(hsP, pos_emb, Wm1, lds, s);
                __syncthreads();
                mlp_step(hsP, bm2, wm, lds, mb, s);
            }
            __syncthreads();  // all reads of Hs(s) done (vmcnt drained per wave)
            if (tid == 0) stf(mf + mb * 32, (unsigned)s);
        }
        __syncthreads();
        if (tid == 0) atomicAdd(lp_out, lds[LP_L]);
    }
}

extern "C" void kernel_launch(void* const* d_in, const int* in_sizes, int n_in,
                              void* d_out, int out_size, void* d_ws, size_t ws_size,
                              hipStream_t stream)
{
    const float* z       = (const float*)d_in[0];
    const int*   targets = (const int*)d_in[1];
    const float* pos_emb = (const float*)d_in[2];
    const float* Ws1     = (const float*)d_in[3];
    const float* Wn1     = (const float*)d_in[4];
    const float* b1      = (const float*)d_in[5];
    const float* Ws2     = (const float*)d_in[6];
    const float* Wn2     = (const float*)d_in[7];
    const float* b2      = (const float*)d_in[8];
    const float* Wm1     = (const float*)d_in[9];
    const float* bm1     = (const float*)d_in[10];
    const float* Wm2     = (const float*)d_in[11];
    const float* bm2     = (const float*)d_in[12];
    const float* Wf      = (const float*)d_in[13];
    const float* bf      = (const float*)d_in[14];
    float* out = (float*)d_out;
    float* ws  = (float*)d_ws;

    // zero prog + mf flag lines and the lp accumulator each call
    (void)hipMemsetAsync(ws + PROG_OFF, 0, (GNN_NB + MLP_NB) * 32 * sizeof(unsigned), stream);
    (void)hipMemsetAsync(out + NN * NN + NN * 16, 0, sizeof(float), stream);

    void* args[17] = {
        (void*)&z, (void*)&targets, (void*)&pos_emb,
        (void*)&Ws1, (void*)&Wn1, (void*)&b1,
        (void*)&Ws2, (void*)&Wn2, (void*)&b2,
        (void*)&Wm1, (void*)&bm1, (void*)&Wm2, (void*)&bm2,
        (void*)&Wf, (void*)&bf, (void*)&out, (void*)&ws
    };
    (void)hipLaunchCooperativeKernel((const void*)fused_gnn, dim3(NBLK), dim3(NTHR),
                                     args, 0, stream);
}